// Round 1
// 337.658 us; speedup vs baseline: 1.0163x; 1.0163x over previous
//
#include <hip/hip_runtime.h>
#include <stdint.h>

typedef unsigned short u16;
typedef __attribute__((ext_vector_type(8))) __bf16 bf16x8;
typedef __attribute__((ext_vector_type(4))) float f32x4;

#define DEVI __device__ __forceinline__

DEVI u16 f32_to_bf16(float f) {
  uint32_t u = __builtin_bit_cast(uint32_t, f);
  u += 0x7FFFu + ((u >> 16) & 1u);   // RNE; inputs are never NaN here
  return (u16)(u >> 16);
}

DEVI void gl2lds16(const void* g, void* l) {
  __builtin_amdgcn_global_load_lds(
      (const __attribute__((address_space(1))) void*)g,
      (__attribute__((address_space(3))) void*)l, 16, 0, 0);
}

// Shared-memory for score/pv: staging (2x 128x64 bf16 = 32KB) unioned with the
// epilogue tile (128x136 bf16 = 34816B, or 64x132 fp32 = 33792B).
#define SMEM_U16 17408  // 34816 bytes

// S is packed triangular: per batch, strip rt (128 rows) has row stride
// (rt+1)*128 and begins at tri(rt)*16384 u16.  Per-batch size 136*16384 u16.
#define S_BATCH 2228224  // u16 elements per batch = 136*16384

// ---------------------------------------------------------------------------
// 128x128 tile bf16 GEMM mainloop (score/pv), "BT" layout:
// C[ar,br] += sum_k A[ar,k]*B[br,k]
// acc[i][j]: A-row = wr*64+i*16+quad*4+r, B-row = wc*64+j*16+l15.
// LDS bank-conflict fix: rotate SOURCE column group per row at staging;
// reads add the same rotation.
// ---------------------------------------------------------------------------
DEVI void gemm_bt_mainloop(const u16* __restrict__ A, const u16* __restrict__ B,
                           int lda, int ldb, int kIters,
                           u16* As, u16* Bs, f32x4 (&acc)[4][4]) {
  const int tid = threadIdx.x;
  const int lane = tid & 63;
  const int wid = tid >> 6;
  const int wr = wid >> 1, wc = wid & 1;
  const int l15 = lane & 15, quad = lane >> 4;

  const int srow = tid >> 3;                  // staged row (plus r*32)
  const int sgrp = ((tid & 7) - srow) & 7;    // rotated source column-group
  const u16* Ag = A + (size_t)srow * lda + sgrp * 8;
  const u16* Bg = B + (size_t)srow * ldb + sgrp * 8;
  char* AsDst = (char*)As + tid * 16;
  char* BsDst = (char*)Bs + tid * 16;

  const int a_row0 = wr * 64 + l15;
  const int b_row0 = wc * 64 + l15;

  for (int kb = 0; kb < kIters; ++kb) {
#pragma unroll
    for (int r = 0; r < 4; ++r) {   // r*32 rows: rotation unchanged (32%8==0)
      gl2lds16(Ag + (size_t)(r * 32) * lda, AsDst + r * 4096);
      gl2lds16(Bg + (size_t)(r * 32) * ldb, BsDst + r * 4096);
    }
    Ag += 64;
    Bg += 64;
    __syncthreads();  // drains vmcnt(0): LDS tiles ready
#pragma unroll
    for (int kk = 0; kk < 2; ++kk) {
      const int gA = ((kk * 4 + quad + a_row0) & 7) * 8;
      const int gB = ((kk * 4 + quad + b_row0) & 7) * 8;
      bf16x8 af[4], bfr[4];
#pragma unroll
      for (int i = 0; i < 4; ++i)
        af[i] = *(const bf16x8*)(As + (a_row0 + i * 16) * 64 + gA);
#pragma unroll
      for (int j = 0; j < 4; ++j)
        bfr[j] = *(const bf16x8*)(Bs + (b_row0 + j * 16) * 64 + gB);
#pragma unroll
      for (int i = 0; i < 4; ++i)
#pragma unroll
        for (int j = 0; j < 4; ++j)
          acc[i][j] = __builtin_amdgcn_mfma_f32_16x16x32_bf16(af[i], bfr[j],
                                                              acc[i][j], 0, 0, 0);
    }
    __syncthreads();
  }
}

// ---------------------------------------------------------------------------
// Stage a 128x128 bf16 tile (LDS, ld=136), store coalesced 16B/lane
DEVI void store_tile_bf16(const u16* tile, u16* __restrict__ out, int ld_out) {
  const int tid = threadIdx.x;
  const int c0 = (tid & 15) * 8;
#pragma unroll
  for (int rr = 0; rr < 8; ++rr) {
    const int row = rr * 16 + (tid >> 4);
    const uint4 v = *(const uint4*)(tile + row * 136 + c0);
    *(uint4*)(out + (size_t)row * ld_out + c0) = v;
  }
}

// ---------------------------------------------------------------------------
__global__ void cast_f32_to_bf16_kernel(const float* __restrict__ src,
                                        u16* __restrict__ dst, int n4) {
  int i = blockIdx.x * blockDim.x + threadIdx.x;
  const int stride = gridDim.x * blockDim.x;
  for (; i < n4; i += stride) {
    const float4 v = ((const float4*)src)[i];
    ushort4 o;
    o.x = f32_to_bf16(v.x);
    o.y = f32_to_bf16(v.y);
    o.z = f32_to_bf16(v.z);
    o.w = f32_to_bf16(v.w);
    ((ushort4*)dst)[i] = o;
  }
}

// weights -> contiguous bf16 [3][1024][1024]; z==3 zero-inits sums[16384].
__global__ void cast_w_kernel(const float* __restrict__ wq,
                              const float* __restrict__ wk,
                              const float* __restrict__ wv,
                              u16* __restrict__ wb, float* __restrict__ sums) {
  const int z = blockIdx.y;
  if (z == 3) {
    int i = blockIdx.x * blockDim.x + threadIdx.x;
    if (i < 4096) ((float4*)sums)[i] = (float4){0.f, 0.f, 0.f, 0.f};
    return;
  }
  const float* src = (z == 0) ? wq : (z == 1) ? wk : wv;
  u16* dst = wb + (size_t)z * 1048576;
  int i = blockIdx.x * blockDim.x + threadIdx.x;
  const int stride = gridDim.x * blockDim.x;
  for (; i < 262144; i += stride) {
    const float4 v = ((const float4*)src)[i];
    ushort4 o;
    o.x = f32_to_bf16(v.x);
    o.y = f32_to_bf16(v.y);
    o.z = f32_to_bf16(v.z);
    o.w = f32_to_bf16(v.w);
    ((ushort4*)dst)[i] = o;
  }
}

// ---------------------------------------------------------------------------
// Fused Q/K/V projection — 256x256-tile, 8-wave, 8-phase schedule (T3+T4+T5).
//
// GEMM: C[m][n] += sum_k A[m][k]*B[n][k], M=N=256, K=1024 (16 K-tiles of 64).
// Waves: wr=wid>>2 (2 M-groups), wc=wid&3 (4 N-groups).  Fragment (qm,qn,i,j):
//   m = qm*128 + wr*64 + i*16 + quad*4 + r   (i=0..3)
//   n = qn*128 + wc*32 + j*16 + l15          (j=0..1)
// LDS 128KB: 2 bufs x {A0,A1,B0,B1} 16KB regions; region X{h} = operand rows
// h*128..h*128+127 of the K-tile, row stride 64 u16, per-row rotated column
// groups (same swizzle as gemm_bt_mainloop -> conflict-free, gl_lds-linear).
//
// Phase p: {ds_read quadrant frags | stage 1 half-tile} barrier lgkmcnt(0)
//          setprio(1) 16xMFMA setprio(0) [vmcnt(6) @P4/P8] barrier.
// Quadrants per K-tile: P1(0,0) P2(0,1) P3(1,1) P4(1,0) — A regs reloaded at
// P3, both B halves stay live.  Stage order (steady, iteration computes K-tiles
// j,j+1): P1:A1(j+1) P2:A0(j+2) P3:B0(j+2) P4:B1(j+2) P5:A1(j+2) P6:A0(j+3)
// P7:B0(j+3) P8:B1(j+3).  vmcnt(6)=3 half-tiles in flight guarantees exactly
// the next K-tile has landed at each P4/P8 (checked by hand, incl. pro/epilog).
// ---------------------------------------------------------------------------
__global__ __launch_bounds__(512, 2) void qkv_kernel(
    const u16* __restrict__ xb, const u16* __restrict__ wb,
    const float* __restrict__ bq, const float* __restrict__ bk,
    const float* __restrict__ bv, u16* __restrict__ Qb, u16* __restrict__ Kb,
    u16* __restrict__ Vt) {
  __shared__ __align__(16) u16 lds[65536];  // 128 KB

  const int id = blockIdx.x;                 // 0..767
  const int wg = (id & 7) * 96 + (id >> 3);  // bijective XCD swizzle (768%8==0)
  const int g = wg >> 3, u = wg & 7;         // groups of 8 tiles: 4c x 2t (~3MB L2)
  const int z = g >> 5;                      // 0..2
  const int tp = g & 31;                     // t-pair
  const int tmt = tp * 2 + (u >> 2);         // t-tile 0..63
  const int tct = u & 3;                     // c-tile 0..3

  // Q/K: A=W (m=c, reg-quad packs c); V: A=x (m=t, reg-quad packs t).
  int m0, n0;
  const u16* Aptr;
  const u16* Bptr;
  if (z < 2) {
    m0 = tct * 256;
    n0 = tmt * 256;
    Aptr = wb + (size_t)z * 1048576 + (size_t)m0 * 1024;
    Bptr = xb + (size_t)n0 * 1024;
  } else {
    m0 = tmt * 256;
    n0 = tct * 256;
    Aptr = xb + (size_t)m0 * 1024;
    Bptr = wb + (size_t)2 * 1048576 + (size_t)n0 * 1024;
  }

  const int tid = threadIdx.x;
  const int srow = tid >> 3;                 // staged row 0..63 (+64 2nd load)
  const int sgrp = ((tid & 7) - srow) & 7;   // rotated source column-group
  const u16* Ag = Aptr + (size_t)srow * 1024 + sgrp * 8;
  const u16* Bg = Bptr + (size_t)srow * 1024 + sgrp * 8;
  char* ldsDst = (char*)lds + tid * 16;

  // Half-tile stagers: 2 x gl_lds x 16B per thread = 128 rows x 64 cols bf16.
#define ST_A0(kt) do { const u16* s_ = Ag + (kt) * 64;           char* d_ = ldsDst + (((kt) & 1) * 65536);         gl2lds16(s_, d_); gl2lds16(s_ + 65536, d_ + 8192); } while (0)
#define ST_A1(kt) do { const u16* s_ = Ag + 131072 + (kt) * 64;  char* d_ = ldsDst + (((kt) & 1) * 65536) + 16384; gl2lds16(s_, d_); gl2lds16(s_ + 65536, d_ + 8192); } while (0)
#define ST_B0(kt) do { const u16* s_ = Bg + (kt) * 64;           char* d_ = ldsDst + (((kt) & 1) * 65536) + 32768; gl2lds16(s_, d_); gl2lds16(s_ + 65536, d_ + 8192); } while (0)
#define ST_B1(kt) do { const u16* s_ = Bg + 131072 + (kt) * 64;  char* d_ = ldsDst + (((kt) & 1) * 65536) + 49152; gl2lds16(s_, d_); gl2lds16(s_ + 65536, d_ + 8192); } while (0)

  // Prologue: K-tile 0 complete + A0/B0/B1 of K-tile 1 (7 half-tiles).
  ST_A0(0); ST_B0(0); ST_B1(0); ST_A1(0);
  ST_A0(1); ST_B0(1); ST_B1(1);

  const int lane = tid & 63, wid = tid >> 6;
  const int wr = wid >> 2, wc = wid & 3;
  const int l15 = lane & 15, quad = lane >> 4;

  int aoff[4][2], boff[2][2];
#pragma unroll
  for (int i_ = 0; i_ < 4; ++i_) {
    const int arow = wr * 64 + i_ * 16 + l15;
#pragma unroll
    for (int k_ = 0; k_ < 2; ++k_)
      aoff[i_][k_] = arow * 64 + ((k_ * 4 + quad + arow) & 7) * 8;
  }
#pragma unroll
  for (int j_ = 0; j_ < 2; ++j_) {
    const int brow = wc * 32 + j_ * 16 + l15;
#pragma unroll
    for (int k_ = 0; k_ < 2; ++k_)
      boff[j_][k_] = brow * 64 + ((k_ * 4 + quad + brow) & 7) * 8;
  }

  f32x4 acc[2][2][4][2];
#pragma unroll
  for (int a_ = 0; a_ < 2; ++a_)
#pragma unroll
    for (int b_ = 0; b_ < 2; ++b_)
#pragma unroll
      for (int i_ = 0; i_ < 4; ++i_)
#pragma unroll
        for (int j_ = 0; j_ < 2; ++j_)
          acc[a_][b_][i_][j_] = (f32x4){0.f, 0.f, 0.f, 0.f};

  bf16x8 af[4][2], bfr[2][2][2];

#define LOADA(qm, buf) do { const u16* p_ = lds + (buf) * 32768 + (qm) * 8192; \
  _Pragma("unroll") for (int i_ = 0; i_ < 4; ++i_) \
  _Pragma("unroll") for (int k_ = 0; k_ < 2; ++k_) \
    af[i_][k_] = *(const bf16x8*)(p_ + aoff[i_][k_]); } while (0)
#define LOADB(qn, buf) do { const u16* p_ = lds + (buf) * 32768 + 16384 + (qn) * 8192; \
  _Pragma("unroll") for (int j_ = 0; j_ < 2; ++j_) \
  _Pragma("unroll") for (int k_ = 0; k_ < 2; ++k_) \
    bfr[qn][j_][k_] = *(const bf16x8*)(p_ + boff[j_][k_]); } while (0)
#define MMA(qm, qn) do { \
  _Pragma("unroll") for (int i_ = 0; i_ < 4; ++i_) \
  _Pragma("unroll") for (int j_ = 0; j_ < 2; ++j_) \
  _Pragma("unroll") for (int k_ = 0; k_ < 2; ++k_) \
    acc[qm][qn][i_][j_] = __builtin_amdgcn_mfma_f32_16x16x32_bf16( \
        af[i_][k_], bfr[qn][j_][k_], acc[qm][qn][i_][j_], 0, 0, 0); } while (0)

#define BAR __builtin_amdgcn_s_barrier()
#define WLG0 asm volatile("s_waitcnt lgkmcnt(0)")
#define WLG8 asm volatile("s_waitcnt lgkmcnt(8)")
#define PRIO1 __builtin_amdgcn_s_setprio(1)
#define PRIO0 __builtin_amdgcn_s_setprio(0)

  asm volatile("s_waitcnt vmcnt(6)" ::: "memory");  // K-tile 0 landed
  BAR;

#pragma unroll 1
  for (int it = 0; it < 7; ++it) {
    const int j0 = 2 * it;
    // P1 (0,0) buf0
    LOADA(0, 0); LOADB(0, 0); ST_A1(j0 + 1); WLG8;
    BAR; WLG0; PRIO1; MMA(0, 0); PRIO0; BAR;
    // P2 (0,1)
    LOADB(1, 0); ST_A0(j0 + 2);
    BAR; WLG0; PRIO1; MMA(0, 1); PRIO0; BAR;
    // P3 (1,1)
    LOADA(1, 0); ST_B0(j0 + 2);
    BAR; WLG0; PRIO1; MMA(1, 1); PRIO0; BAR;
    // P4 (1,0)
    ST_B1(j0 + 2);
    BAR; PRIO1; MMA(1, 0); PRIO0;
    asm volatile("s_waitcnt vmcnt(6)" ::: "memory");  // K-tile j0+1 landed
    BAR;
    // P5 (0,0) buf1
    LOADA(0, 1); LOADB(0, 1); ST_A1(j0 + 2); WLG8;
    BAR; WLG0; PRIO1; MMA(0, 0); PRIO0; BAR;
    // P6 (0,1)
    LOADB(1, 1); ST_A0(j0 + 3);
    BAR; WLG0; PRIO1; MMA(0, 1); PRIO0; BAR;
    // P7 (1,1)
    LOADA(1, 1); ST_B0(j0 + 3);
    BAR; WLG0; PRIO1; MMA(1, 1); PRIO0; BAR;
    // P8 (1,0)
    ST_B1(j0 + 3);
    BAR; PRIO1; MMA(1, 0); PRIO0;
    asm volatile("s_waitcnt vmcnt(6)" ::: "memory");  // K-tile j0+2 landed
    BAR;
  }
  {  // it = 7: K-tiles 14 (buf0) / 15 (buf1); only A1(15) left to stage
    LOADA(0, 0); LOADB(0, 0); ST_A1(15); WLG8;
    BAR; WLG0; PRIO1; MMA(0, 0); PRIO0; BAR;
    LOADB(1, 0);
    BAR; WLG0; PRIO1; MMA(0, 1); PRIO0; BAR;
    LOADA(1, 0);
    BAR; WLG0; PRIO1; MMA(1, 1); PRIO0; BAR;
    PRIO1; MMA(1, 0); PRIO0;
    asm volatile("s_waitcnt vmcnt(0)" ::: "memory");  // drain: K-tile 15 landed
    BAR;
    LOADA(0, 1); LOADB(0, 1); WLG8;
    BAR; WLG0; PRIO1; MMA(0, 0); PRIO0; BAR;
    LOADB(1, 1);
    BAR; WLG0; PRIO1; MMA(0, 1); PRIO0; BAR;
    LOADA(1, 1);
    BAR; WLG0; PRIO1; MMA(1, 1); PRIO0; BAR;
    PRIO1; MMA(1, 0); PRIO0;
    BAR;  // mainloop done; LDS reusable (all gl_lds drained at vmcnt(0))
  }

  // Epilogue: per N-half th, stage [128 n-rows][256 m-cols] (+8 pad) in LDS,
  // then full-line 16B/lane global stores.
  if (z < 2) {
    const float* bias = (z == 0) ? bq : bk;
    u16* Out = (z == 0) ? Qb : Kb;
#pragma unroll
    for (int th = 0; th < 2; ++th) {
      if (th) __syncthreads();
#pragma unroll
      for (int qm = 0; qm < 2; ++qm)
#pragma unroll
        for (int i_ = 0; i_ < 4; ++i_) {
          const int c = qm * 128 + wr * 64 + i_ * 16 + quad * 4;
          const float4 b4 = *(const float4*)(bias + m0 + c);
#pragma unroll
          for (int j_ = 0; j_ < 2; ++j_) {
            const int row = wc * 32 + j_ * 16 + l15;
            ushort4 o;
            o.x = f32_to_bf16(acc[qm][th][i_][j_][0] + b4.x);
            o.y = f32_to_bf16(acc[qm][th][i_][j_][1] + b4.y);
            o.z = f32_to_bf16(acc[qm][th][i_][j_][2] + b4.z);
            o.w = f32_to_bf16(acc[qm][th][i_][j_][3] + b4.w);
            *(ushort4*)(lds + row * 264 + c) = o;   // [t][c]
          }
        }
      __syncthreads();
#pragma unroll
      for (int p = 0; p < 8; ++p) {
        const int row = p * 16 + (tid >> 5);
        const int c0 = (tid & 31) * 8;
        const uint4 v = *(const uint4*)(lds + row * 264 + c0);
        *(uint4*)(Out + (size_t)(n0 + th * 128 + row) * 1024 + m0 + c0) = v;
      }
    }
  } else {
    const int b = m0 >> 11;
    const int t0b = m0 & 2047;
    u16* Out = Vt + (size_t)b * 2097152;
#pragma unroll
    for (int th = 0; th < 2; ++th) {
      if (th) __syncthreads();
#pragma unroll
      for (int j_ = 0; j_ < 2; ++j_) {
        const int row = wc * 32 + j_ * 16 + l15;      // c within half
        const float bb = bv[n0 + th * 128 + row];
#pragma unroll
        for (int qm = 0; qm < 2; ++qm)
#pragma unroll
          for (int i_ = 0; i_ < 4; ++i_) {
            const int c = qm * 128 + wr * 64 + i_ * 16 + quad * 4;  // t
            ushort4 o;
            o.x = f32_to_bf16(acc[qm][th][i_][j_][0] + bb);
            o.y = f32_to_bf16(acc[qm][th][i_][j_][1] + bb);
            o.z = f32_to_bf16(acc[qm][th][i_][j_][2] + bb);
            o.w = f32_to_bf16(acc[qm][th][i_][j_][3] + bb);
            *(ushort4*)(lds + row * 264 + c) = o;     // [c][t]
          }
      }
      __syncthreads();
#pragma unroll
      for (int p = 0; p < 8; ++p) {
        const int row = p * 16 + (tid >> 5);
        const int c0 = (tid & 31) * 8;
        const uint4 v = *(const uint4*)(lds + row * 264 + c0);
        *(uint4*)(Out + (size_t)(n0 + th * 128 + row) * 2048 + t0b + c0) = v;
      }
    }
  }
#undef ST_A0
#undef ST_A1
#undef ST_B0
#undef ST_B1
#undef LOADA
#undef LOADB
#undef MMA
#undef BAR
#undef WLG0
#undef WLG8
#undef PRIO1
#undef PRIO0
}

// ---------------------------------------------------------------------------
// S[b][t][s] = exp((K[b,t,:].Q[b,s,:])/32), unnormalized, causal-masked,
// written into the PACKED triangular strip.  A = Q rows (s-dim) so the acc
// reg-quad packs 4 consecutive s.  Row sums -> atomicAdd(sums[b][t]).
__global__ __launch_bounds__(256) void score_kernel(const u16* __restrict__ Kb,
                                                    const u16* __restrict__ Qb,
                                                    u16* __restrict__ Spk,
                                                    float* __restrict__ sums) {
  const int b = blockIdx.x & 7;
  const int l = 135 - (blockIdx.x >> 3);  // 0..135, descending work
  int rt = (int)((sqrtf(8.f * l + 1.f) - 1.f) * 0.5f);
  int ct = l - rt * (rt + 1) / 2;
  if (ct > rt) { ++rt; ct = l - rt * (rt + 1) / 2; }
  if (ct < 0)  { --rt; ct = l - rt * (rt + 1) / 2; }

  __shared__ __align__(16) u16 smem[SMEM_U16];
  u16* As = smem;
  u16* Bs = smem + 8192;

  f32x4 acc[4][4];
#pragma unroll
  for (int i = 0; i < 4; ++i)
#pragma unroll
    for (int j = 0; j < 4; ++j) acc[i][j] = (f32x4){0.f, 0.f, 0.f, 0.f};

  const u16* A = Qb + ((size_t)b * 2048 + ct * 128) * 1024;  // rows = s
  const u16* B = Kb + ((size_t)b * 2048 + rt * 128) * 1024;  // rows = t
  gemm_bt_mainloop(A, B, 1024, 1024, 16, As, Bs, acc);

  const int tid = threadIdx.x;
  const int lane = tid & 63, wid = tid >> 6;
  const int wr = wid >> 1, wc = wid & 1;
  const int l15 = lane & 15, quad = lane >> 4;
  const bool diag = (rt == ct);

  float sj[4] = {0.f, 0.f, 0.f, 0.f};
#pragma unroll
  for (int i = 0; i < 4; ++i) {
    const int s0 = wr * 64 + i * 16 + quad * 4;
#pragma unroll
    for (int j = 0; j < 4; ++j) {
      const int t = wc * 64 + j * 16 + l15;
      ushort4 o;
      float e[4];
#pragma unroll
      for (int r = 0; r < 4; ++r) {
        float v = __expf(acc[i][j][r] * 0.03125f);
        if (diag && (s0 + r) > t) v = 0.f;   // causal mask in diag tile
        e[r] = v;
        sj[j] += v;
      }
      o.x = f32_to_bf16(e[0]);
      o.y = f32_to_bf16(e[1]);
      o.z = f32_to_bf16(e[2]);
      o.w = f32_to_bf16(e[3]);
      *(ushort4*)(smem + t * 136 + s0) = o;   // [t][s] tile
    }
  }
  // reduce each t's partial (this wave's 64-s slice) across the 4 quads
#pragma unroll
  for (int j = 0; j < 4; ++j) {
    float v = sj[j];
    v += __shfl_xor(v, 16);
    v += __shfl_xor(v, 32);
    if (quad == 0)
      atomicAdd(&sums[(size_t)b * 2048 + rt * 128 + wc * 64 + j * 16 + l15], v);
  }
  __syncthreads();
  const int ld = (rt + 1) * 128;
  u16* Out = Spk + (size_t)b * S_BATCH + (size_t)(rt * (rt + 1) / 2) * 16384 +
             ct * 128;
  store_tile_bf16(smem, Out, ld);
}

// ---------------------------------------------------------------------------
// out[b][t][c] = (1/sums[b][t]) * sum_s S[b][t][s] * Vt[b][c][s].
__global__ __launch_bounds__(256) void pv_kernel(const u16* __restrict__ Spk,
                                                 const u16* __restrict__ Vt,
                                                 const float* __restrict__ sums,
                                                 float* __restrict__ Out) {
  const int b = blockIdx.x & 7;
  const int local = 127 - (blockIdx.x >> 3);  // 0..127 descending work
  const int rt = local >> 3;
  const int ct = local & 7;

  __shared__ __align__(16) u16 smem[SMEM_U16];
  u16* As = smem;
  u16* Bs = smem + 8192;
  float* ftile = (float*)smem;  // 64(t) x 132(c) fp32 = 33792B

  f32x4 acc[4][4];
#pragma unroll
  for (int i = 0; i < 4; ++i)
#pragma unroll
    for (int j = 0; j < 4; ++j) acc[i][j] = (f32x4){0.f, 0.f, 0.f, 0.f};

  const u16* A = Vt + ((size_t)b * 1024 + ct * 128) * 2048;  // rows = c
  const u16* B = Spk + (size_t)b * S_BATCH +
                 (size_t)(rt * (rt + 1) / 2) * 16384;        // rows = t
  const int ldb = (rt + 1) * 128;
  gemm_bt_mainloop(A, B, 2048, ldb, (rt + 1) * 2, As, Bs, acc);

  const int tid = threadIdx.x;
  const int lane = tid & 63, wid = tid >> 6;
  const int wr = wid >> 1, wc = wid & 1;
  const int l15 = lane & 15, quad = lane >> 4;

  const float* sumsb = sums + (size_t)b * 2048 + rt * 128;
  float* Ob = Out + (size_t)b * 2048 * 1024 + (size_t)(rt * 128) * 1024 +
              ct * 128;
#pragma unroll
  for (int h = 0; h < 2; ++h) {   // t-halves by wc
    if (wc == h) {
#pragma unroll
      for (int j = 0; j < 4; ++j) {
        const int tl = j * 16 + l15;                  // t within half
        const float iv = 1.0f / sumsb[h * 64 + tl];
#pragma unroll
        for (int i = 0; i < 4; ++i) {
          const int c0 = wr * 64 + i * 16 + quad * 4;
          float4 v;
          v.x = acc[i][j][0] * iv;
          v.y = acc[i][j][1] * iv;
          v.z = acc[i][j][2] * iv;
          v.w = acc[i][j][3] * iv;
          *(float4*)(ftile + tl * 132 + c0) = v;
        }
      }
    }
    __syncthreads();
#pragma unroll
    for (int rr = 0; rr < 8; ++rr) {
      const int row = rr * 8 + (tid >> 5);        // 8 rows/iter x 8 = 64 rows
      const int c0 = (tid & 31) * 4;              // 32 lanes x 4 f32 = 128 col
      const float4 v = *(const float4*)(ftile + row * 132 + c0);
      *(float4*)(Ob + (size_t)(h * 64 + row) * 1024 + c0) = v;
    }
    __syncthreads();
  }
}

// ---------------------------------------------------------------------------
extern "C" void kernel_launch(void* const* d_in, const int* in_sizes, int n_in,
                              void* d_out, int out_size, void* d_ws,
                              size_t ws_size, hipStream_t stream) {
  const float* x = (const float*)d_in[0];
  const float* wq = (const float*)d_in[1];
  const float* bq = (const float*)d_in[2];
  const float* wk = (const float*)d_in[3];
  const float* bk = (const float*)d_in[4];
  const float* wv = (const float*)d_in[5];
  const float* bv = (const float*)d_in[6];
  float* out = (float*)d_out;
  char* ws = (char*)d_ws;

  // Workspace layout (<=160 MB):
  //   [0,32M)      Qb bf16 [16384][1024]
  //   [32,64M)     Kb bf16 [16384][1024]
  //   [64,96M)     Vt bf16 [8][1024][2048]
  //   [96,130.1M)  Spk bf16 packed triangular [8][136*16384]
  //   [132,132.07M) sums fp32 [16384]
  //   [134,140M)   wb bf16 [3][1024][1024]
  //   xb (32MB @96M) aliases Spk: dead after qkv pass.
  u16* Qb = (u16*)(ws);
  u16* Kb = (u16*)(ws + ((size_t)32 << 20));
  u16* Vt = (u16*)(ws + ((size_t)64 << 20));
  u16* Spk = (u16*)(ws + ((size_t)96 << 20));
  u16* xb = (u16*)(ws + ((size_t)96 << 20));   // alias: dies before Spk written
  float* sums = (float*)(ws + ((size_t)132 << 20));
  u16* wb = (u16*)(ws + ((size_t)134 << 20));

  // pass 0: casts + sums zero-init
  cast_f32_to_bf16_kernel<<<16384, 256, 0, stream>>>(x, xb, 16777216 / 4);
  cast_w_kernel<<<dim3(512, 4), 256, 0, stream>>>(wq, wk, wv, wb, sums);

  // pass 1: fused Q,K,V projections (V transposed), 256^2 8-phase
  qkv_kernel<<<768, 512, 0, stream>>>(xb, wb, bq, bk, bv, Qb, Kb, Vt);

  // pass 2: causal exp-scores (unnormalized, packed) + atomic row sums
  score_kernel<<<8 * 136, 256, 0, stream>>>(Kb, Qb, Spk, sums);

  // pass 3: P @ V scaled by 1/sums
  pv_kernel<<<8 * 128, 256, 0, stream>>>(Spk, Vt, sums, out);
}

// Round 2
// 333.271 us; speedup vs baseline: 1.0297x; 1.0132x over previous
//
#include <hip/hip_runtime.h>
#include <stdint.h>

typedef unsigned short u16;
typedef __attribute__((ext_vector_type(8))) __bf16 bf16x8;
typedef __attribute__((ext_vector_type(4))) float f32x4;

#define DEVI __device__ __forceinline__

DEVI u16 f32_to_bf16(float f) {
  uint32_t u = __builtin_bit_cast(uint32_t, f);
  u += 0x7FFFu + ((u >> 16) & 1u);   // RNE; inputs are never NaN here
  return (u16)(u >> 16);
}

DEVI void gl2lds16(const void* g, void* l) {
  __builtin_amdgcn_global_load_lds(
      (const __attribute__((address_space(1))) void*)g,
      (__attribute__((address_space(3))) void*)l, 16, 0, 0);
}

// Shared-memory for pv: staging (2x 128x64 bf16 = 32KB) unioned with the
// epilogue tile (64x132 fp32 = 33792B).
#define SMEM_U16 17408  // 34816 bytes

// S is packed triangular: per batch, strip rt (128 rows) has row stride
// (rt+1)*128 and begins at tri(rt)*16384 u16.  Per-batch size 136*16384 u16.
#define S_BATCH 2228224  // u16 elements per batch = 136*16384

// ---------------------------------------------------------------------------
// 128x128 tile bf16 GEMM mainloop (pv), "BT" layout:
// C[ar,br] += sum_k A[ar,k]*B[br,k]
// acc[i][j]: A-row = wr*64+i*16+quad*4+r, B-row = wc*64+j*16+l15.
// LDS bank-conflict fix: rotate SOURCE column group per row at staging;
// reads add the same rotation.
// ---------------------------------------------------------------------------
DEVI void gemm_bt_mainloop(const u16* __restrict__ A, const u16* __restrict__ B,
                           int lda, int ldb, int kIters,
                           u16* As, u16* Bs, f32x4 (&acc)[4][4]) {
  const int tid = threadIdx.x;
  const int lane = tid & 63;
  const int wid = tid >> 6;
  const int wr = wid >> 1, wc = wid & 1;
  const int l15 = lane & 15, quad = lane >> 4;

  const int srow = tid >> 3;                  // staged row (plus r*32)
  const int sgrp = ((tid & 7) - srow) & 7;    // rotated source column-group
  const u16* Ag = A + (size_t)srow * lda + sgrp * 8;
  const u16* Bg = B + (size_t)srow * ldb + sgrp * 8;
  char* AsDst = (char*)As + tid * 16;
  char* BsDst = (char*)Bs + tid * 16;

  const int a_row0 = wr * 64 + l15;
  const int b_row0 = wc * 64 + l15;

  for (int kb = 0; kb < kIters; ++kb) {
#pragma unroll
    for (int r = 0; r < 4; ++r) {   // r*32 rows: rotation unchanged (32%8==0)
      gl2lds16(Ag + (size_t)(r * 32) * lda, AsDst + r * 4096);
      gl2lds16(Bg + (size_t)(r * 32) * ldb, BsDst + r * 4096);
    }
    Ag += 64;
    Bg += 64;
    __syncthreads();  // drains vmcnt(0): LDS tiles ready
#pragma unroll
    for (int kk = 0; kk < 2; ++kk) {
      const int gA = ((kk * 4 + quad + a_row0) & 7) * 8;
      const int gB = ((kk * 4 + quad + b_row0) & 7) * 8;
      bf16x8 af[4], bfr[4];
#pragma unroll
      for (int i = 0; i < 4; ++i)
        af[i] = *(const bf16x8*)(As + (a_row0 + i * 16) * 64 + gA);
#pragma unroll
      for (int j = 0; j < 4; ++j)
        bfr[j] = *(const bf16x8*)(Bs + (b_row0 + j * 16) * 64 + gB);
#pragma unroll
      for (int i = 0; i < 4; ++i)
#pragma unroll
        for (int j = 0; j < 4; ++j)
          acc[i][j] = __builtin_amdgcn_mfma_f32_16x16x32_bf16(af[i], bfr[j],
                                                              acc[i][j], 0, 0, 0);
    }
    __syncthreads();
  }
}

// ---------------------------------------------------------------------------
__global__ void cast_f32_to_bf16_kernel(const float* __restrict__ src,
                                        u16* __restrict__ dst, int n4) {
  int i = blockIdx.x * blockDim.x + threadIdx.x;
  const int stride = gridDim.x * blockDim.x;
  for (; i < n4; i += stride) {
    const float4 v = ((const float4*)src)[i];
    ushort4 o;
    o.x = f32_to_bf16(v.x);
    o.y = f32_to_bf16(v.y);
    o.z = f32_to_bf16(v.z);
    o.w = f32_to_bf16(v.w);
    ((ushort4*)dst)[i] = o;
  }
}

// weights -> contiguous bf16 [3][1024][1024]; z==3 zero-inits sums[16384].
__global__ void cast_w_kernel(const float* __restrict__ wq,
                              const float* __restrict__ wk,
                              const float* __restrict__ wv,
                              u16* __restrict__ wb, float* __restrict__ sums) {
  const int z = blockIdx.y;
  if (z == 3) {
    int i = blockIdx.x * blockDim.x + threadIdx.x;
    if (i < 4096) ((float4*)sums)[i] = (float4){0.f, 0.f, 0.f, 0.f};
    return;
  }
  const float* src = (z == 0) ? wq : (z == 1) ? wk : wv;
  u16* dst = wb + (size_t)z * 1048576;
  int i = blockIdx.x * blockDim.x + threadIdx.x;
  const int stride = gridDim.x * blockDim.x;
  for (; i < 262144; i += stride) {
    const float4 v = ((const float4*)src)[i];
    ushort4 o;
    o.x = f32_to_bf16(v.x);
    o.y = f32_to_bf16(v.y);
    o.z = f32_to_bf16(v.z);
    o.w = f32_to_bf16(v.w);
    ((ushort4*)dst)[i] = o;
  }
}

// ---------------------------------------------------------------------------
// Fused Q/K/V projection — 256x256-tile, 8-wave, 8-phase with READ-AHEAD:
// each phase's MFMA consumes ds_reads issued in the PREVIOUS phase's MFMA
// region, so lgkmcnt(0) is pre-satisfied.  Hazard ledger (hand-checked):
// every ST that overwrites region X is issued >= 1 end-barrier after the
// all-wave drain (WLG0+barrier) of X's last reader; all cross-buffer reads
// are issued after the vmcnt(6)+barrier pair (per-wave vmcnt does not order
// other waves' staging).
// ---------------------------------------------------------------------------
__global__ __launch_bounds__(512, 2) void qkv_kernel(
    const u16* __restrict__ xb, const u16* __restrict__ wb,
    const float* __restrict__ bq, const float* __restrict__ bk,
    const float* __restrict__ bv, u16* __restrict__ Qb, u16* __restrict__ Kb,
    u16* __restrict__ Vt) {
  __shared__ __align__(16) u16 lds[65536];  // 128 KB

  const int id = blockIdx.x;                 // 0..767
  const int wg = (id & 7) * 96 + (id >> 3);  // bijective XCD swizzle (768%8==0)
  const int g = wg >> 3, u = wg & 7;         // groups of 8 tiles: 4c x 2t (~3MB L2)
  const int z = g >> 5;                      // 0..2
  const int tp = g & 31;                     // t-pair
  const int tmt = tp * 2 + (u >> 2);         // t-tile 0..63
  const int tct = u & 3;                     // c-tile 0..3

  // Q/K: A=W (m=c, reg-quad packs c); V: A=x (m=t, reg-quad packs t).
  int m0, n0;
  const u16* Aptr;
  const u16* Bptr;
  if (z < 2) {
    m0 = tct * 256;
    n0 = tmt * 256;
    Aptr = wb + (size_t)z * 1048576 + (size_t)m0 * 1024;
    Bptr = xb + (size_t)n0 * 1024;
  } else {
    m0 = tmt * 256;
    n0 = tct * 256;
    Aptr = xb + (size_t)m0 * 1024;
    Bptr = wb + (size_t)2 * 1048576 + (size_t)n0 * 1024;
  }

  const int tid = threadIdx.x;
  const int srow = tid >> 3;                 // staged row 0..63 (+64 2nd load)
  const int sgrp = ((tid & 7) - srow) & 7;   // rotated source column-group
  const u16* Ag = Aptr + (size_t)srow * 1024 + sgrp * 8;
  const u16* Bg = Bptr + (size_t)srow * 1024 + sgrp * 8;
  char* ldsDst = (char*)lds + tid * 16;

  // Half-tile stagers: 2 x gl_lds x 16B per thread = 128 rows x 64 cols bf16.
#define ST_A0(kt) do { const u16* s_ = Ag + (kt) * 64;           char* d_ = ldsDst + (((kt) & 1) * 65536);         gl2lds16(s_, d_); gl2lds16(s_ + 65536, d_ + 8192); } while (0)
#define ST_A1(kt) do { const u16* s_ = Ag + 131072 + (kt) * 64;  char* d_ = ldsDst + (((kt) & 1) * 65536) + 16384; gl2lds16(s_, d_); gl2lds16(s_ + 65536, d_ + 8192); } while (0)
#define ST_B0(kt) do { const u16* s_ = Bg + (kt) * 64;           char* d_ = ldsDst + (((kt) & 1) * 65536) + 32768; gl2lds16(s_, d_); gl2lds16(s_ + 65536, d_ + 8192); } while (0)
#define ST_B1(kt) do { const u16* s_ = Bg + 131072 + (kt) * 64;  char* d_ = ldsDst + (((kt) & 1) * 65536) + 49152; gl2lds16(s_, d_); gl2lds16(s_ + 65536, d_ + 8192); } while (0)

  // Prologue: K-tile 0 complete + A0/B0/B1 of K-tile 1 (7 half-tiles).
  ST_A0(0); ST_B0(0); ST_B1(0); ST_A1(0);
  ST_A0(1); ST_B0(1); ST_B1(1);

  const int lane = tid & 63, wid = tid >> 6;
  const int wr = wid >> 2, wc = wid & 3;
  const int l15 = lane & 15, quad = lane >> 4;

  int aoff[4][2], boff[2][2];
#pragma unroll
  for (int i_ = 0; i_ < 4; ++i_) {
    const int arow = wr * 64 + i_ * 16 + l15;
#pragma unroll
    for (int k_ = 0; k_ < 2; ++k_)
      aoff[i_][k_] = arow * 64 + ((k_ * 4 + quad + arow) & 7) * 8;
  }
#pragma unroll
  for (int j_ = 0; j_ < 2; ++j_) {
    const int brow = wc * 32 + j_ * 16 + l15;
#pragma unroll
    for (int k_ = 0; k_ < 2; ++k_)
      boff[j_][k_] = brow * 64 + ((k_ * 4 + quad + brow) & 7) * 8;
  }

  f32x4 acc[2][2][4][2];
#pragma unroll
  for (int a_ = 0; a_ < 2; ++a_)
#pragma unroll
    for (int b_ = 0; b_ < 2; ++b_)
#pragma unroll
      for (int i_ = 0; i_ < 4; ++i_)
#pragma unroll
        for (int j_ = 0; j_ < 2; ++j_)
          acc[a_][b_][i_][j_] = (f32x4){0.f, 0.f, 0.f, 0.f};

  bf16x8 af[4][2], bfr[2][2][2];

#define LOADA(qm, buf) do { const u16* p_ = lds + (buf) * 32768 + (qm) * 8192; \
  _Pragma("unroll") for (int i_ = 0; i_ < 4; ++i_) \
  _Pragma("unroll") for (int k_ = 0; k_ < 2; ++k_) \
    af[i_][k_] = *(const bf16x8*)(p_ + aoff[i_][k_]); } while (0)
#define LOADB(qn, buf) do { const u16* p_ = lds + (buf) * 32768 + 16384 + (qn) * 8192; \
  _Pragma("unroll") for (int j_ = 0; j_ < 2; ++j_) \
  _Pragma("unroll") for (int k_ = 0; k_ < 2; ++k_) \
    bfr[qn][j_][k_] = *(const bf16x8*)(p_ + boff[j_][k_]); } while (0)
#define MMA(qm, qn) do { \
  _Pragma("unroll") for (int i_ = 0; i_ < 4; ++i_) \
  _Pragma("unroll") for (int j_ = 0; j_ < 2; ++j_) \
  _Pragma("unroll") for (int k_ = 0; k_ < 2; ++k_) \
    acc[qm][qn][i_][j_] = __builtin_amdgcn_mfma_f32_16x16x32_bf16( \
        af[i_][k_], bfr[qn][j_][k_], acc[qm][qn][i_][j_], 0, 0, 0); } while (0)

#define BAR __builtin_amdgcn_s_barrier()
#define WLG0 asm volatile("s_waitcnt lgkmcnt(0)")
#define PRIO1 __builtin_amdgcn_s_setprio(1)
#define PRIO0 __builtin_amdgcn_s_setprio(0)
#define WVM6 asm volatile("s_waitcnt vmcnt(6)" ::: "memory")
#define WVM0 asm volatile("s_waitcnt vmcnt(0)" ::: "memory")

  WVM6;  // K-tile 0 landed
  BAR;

#pragma unroll 1
  for (int it = 0; it < 7; ++it) {
    const int j0 = 2 * it;
    // P1 (0,0) buf0 — boundary reads phase-local; read-ahead bfr[1] for P2
    LOADA(0, 0); LOADB(0, 0); ST_A1(j0 + 1);
    BAR; WLG0; PRIO1; MMA(0, 0); PRIO0; LOADB(1, 0); BAR;
    // P2 (0,1) — read-ahead af(qm=1) for P3
    ST_A0(j0 + 2);
    BAR; WLG0; PRIO1; MMA(0, 1); PRIO0; LOADA(1, 0); BAR;
    // P3 (1,1)
    ST_B0(j0 + 2);
    BAR; WLG0; PRIO1; MMA(1, 1); PRIO0; BAR;
    // P4 (1,0) — register reuse, no reads
    ST_B1(j0 + 2);
    BAR; PRIO1; MMA(1, 0); PRIO0;
    WVM6;  // K-tile j0+1 landed (own-wave); barrier makes it all-wave
    BAR;
    // P5 (0,0) buf1
    LOADA(0, 1); LOADB(0, 1); ST_A1(j0 + 2);
    BAR; WLG0; PRIO1; MMA(0, 0); PRIO0; LOADB(1, 1); BAR;
    // P6 (0,1)
    ST_A0(j0 + 3);
    BAR; WLG0; PRIO1; MMA(0, 1); PRIO0; LOADA(1, 1); BAR;
    // P7 (1,1)
    ST_B0(j0 + 3);
    BAR; WLG0; PRIO1; MMA(1, 1); PRIO0; BAR;
    // P8 (1,0)
    ST_B1(j0 + 3);
    BAR; PRIO1; MMA(1, 0); PRIO0;
    WVM6;  // K-tile j0+2 landed
    BAR;
  }
  {  // it = 7: K-tiles 14 (buf0) / 15 (buf1); only A1(15) left to stage
    LOADA(0, 0); LOADB(0, 0); ST_A1(15);
    BAR; WLG0; PRIO1; MMA(0, 0); PRIO0; LOADB(1, 0); BAR;
    BAR; WLG0; PRIO1; MMA(0, 1); PRIO0; LOADA(1, 0); BAR;
    BAR; WLG0; PRIO1; MMA(1, 1); PRIO0; BAR;
    BAR; PRIO1; MMA(1, 0); PRIO0;
    WVM0;  // drain: K-tile 15 landed
    BAR;
    LOADA(0, 1); LOADB(0, 1);
    BAR; WLG0; PRIO1; MMA(0, 0); PRIO0; LOADB(1, 1); BAR;
    BAR; WLG0; PRIO1; MMA(0, 1); PRIO0; LOADA(1, 1); BAR;
    BAR; WLG0; PRIO1; MMA(1, 1); PRIO0; BAR;
    PRIO1; MMA(1, 0); PRIO0;
    // all LDS reads drained before the last barrier; epilogue may reuse LDS
  }

  // Epilogue: per N-half th, stage [128 n-rows][256 m-cols] (+8 pad) in LDS,
  // then full-line 16B/lane global stores.
  if (z < 2) {
    const float* bias = (z == 0) ? bq : bk;
    u16* Out = (z == 0) ? Qb : Kb;
#pragma unroll
    for (int th = 0; th < 2; ++th) {
      if (th) __syncthreads();
#pragma unroll
      for (int qm = 0; qm < 2; ++qm)
#pragma unroll
        for (int i_ = 0; i_ < 4; ++i_) {
          const int c = qm * 128 + wr * 64 + i_ * 16 + quad * 4;
          const float4 b4 = *(const float4*)(bias + m0 + c);
#pragma unroll
          for (int j_ = 0; j_ < 2; ++j_) {
            const int row = wc * 32 + j_ * 16 + l15;
            ushort4 o;
            o.x = f32_to_bf16(acc[qm][th][i_][j_][0] + b4.x);
            o.y = f32_to_bf16(acc[qm][th][i_][j_][1] + b4.y);
            o.z = f32_to_bf16(acc[qm][th][i_][j_][2] + b4.z);
            o.w = f32_to_bf16(acc[qm][th][i_][j_][3] + b4.w);
            *(ushort4*)(lds + row * 264 + c) = o;   // [t][c]
          }
        }
      __syncthreads();
#pragma unroll
      for (int p = 0; p < 8; ++p) {
        const int row = p * 16 + (tid >> 5);
        const int c0 = (tid & 31) * 8;
        const uint4 v = *(const uint4*)(lds + row * 264 + c0);
        *(uint4*)(Out + (size_t)(n0 + th * 128 + row) * 1024 + m0 + c0) = v;
      }
    }
  } else {
    const int b = m0 >> 11;
    const int t0b = m0 & 2047;
    u16* Out = Vt + (size_t)b * 2097152;
#pragma unroll
    for (int th = 0; th < 2; ++th) {
      if (th) __syncthreads();
#pragma unroll
      for (int j_ = 0; j_ < 2; ++j_) {
        const int row = wc * 32 + j_ * 16 + l15;      // c within half
        const float bb = bv[n0 + th * 128 + row];
#pragma unroll
        for (int qm = 0; qm < 2; ++qm)
#pragma unroll
          for (int i_ = 0; i_ < 4; ++i_) {
            const int c = qm * 128 + wr * 64 + i_ * 16 + quad * 4;  // t
            ushort4 o;
            o.x = f32_to_bf16(acc[qm][th][i_][j_][0] + bb);
            o.y = f32_to_bf16(acc[qm][th][i_][j_][1] + bb);
            o.z = f32_to_bf16(acc[qm][th][i_][j_][2] + bb);
            o.w = f32_to_bf16(acc[qm][th][i_][j_][3] + bb);
            *(ushort4*)(lds + row * 264 + c) = o;     // [c][t]
          }
      }
      __syncthreads();
#pragma unroll
      for (int p = 0; p < 8; ++p) {
        const int row = p * 16 + (tid >> 5);
        const int c0 = (tid & 31) * 8;
        const uint4 v = *(const uint4*)(lds + row * 264 + c0);
        *(uint4*)(Out + (size_t)(n0 + th * 128 + row) * 2048 + t0b + c0) = v;
      }
    }
  }
#undef ST_A0
#undef ST_A1
#undef ST_B0
#undef ST_B1
#undef LOADA
#undef LOADB
#undef MMA
#undef BAR
#undef WLG0
#undef PRIO1
#undef PRIO0
#undef WVM6
#undef WVM0
}

// ---------------------------------------------------------------------------
// Scores — 256(s) x 128(t) tile, 8 waves, 2 phases/K-tile, read-ahead.
// S[b][t][s] = exp((K.Q)/32), causal-masked, packed triangular (layout
// unchanged from pv's point of view).  A = Q rows (s): reg-quad packs s so
// both row-sum (over s) and the [t][s] staging vectorize.
// Fragment: s = qm*128 + wr*64 + i*16 + quad*4 + r ; t = wc*32 + j*16 + l15.
// LDS 96KB: 2 bufs x {A0,A1,B} x 16KB (row stride 64 u16, rotated groups).
// Grid 576 = 8 batches (one per XCD) x 72 tiles; all tiles equal cost.
// Tile decode: l -> k = max k with k(k+1)<=l; off=l-k(k+1);
//   rt = 2k + (off>=k+1); ct = off mod (k+1); last tile (ct==k) is masked.
// Even-rt last tile clips to 128 stored cols (right half all above diag).
// ---------------------------------------------------------------------------
__global__ __launch_bounds__(512, 2) void score_kernel(const u16* __restrict__ Kb,
                                                       const u16* __restrict__ Qb,
                                                       u16* __restrict__ Spk,
                                                       float* __restrict__ sums) {
  __shared__ __align__(16) u16 lds[49152];  // 96 KB

  const int id = blockIdx.x;   // 0..575
  const int b = id & 7;        // batch per XCD: K/Q tiles stay in XCD L2
  const int l = id >> 3;       // 0..71
  int k = (int)((sqrtf(4.f * l + 1.f) - 1.f) * 0.5f);
  if (k * (k + 1) > l) --k;
  if ((k + 1) * (k + 2) <= l) ++k;
  const int off = l - k * (k + 1);
  const int hi = (off >= (k + 1));
  const int rt = 2 * k + hi;           // t-strip 0..15 (128 rows)
  const int ct = off - (hi ? (k + 1) : 0);  // s-tile 0..k (256 cols)
  const bool maskT = (ct == k);        // only the last s-tile crosses diag

  const int tid = threadIdx.x;
  const int srow = tid >> 3;
  const int sgrp = ((tid & 7) - srow) & 7;
  const u16* A = Qb + ((size_t)b * 2048 + ct * 256) * 1024;  // 256 s-rows
  const u16* B = Kb + ((size_t)b * 2048 + rt * 128) * 1024;  // 128 t-rows
  const u16* Ag = A + (size_t)srow * 1024 + sgrp * 8;
  const u16* Bg = B + (size_t)srow * 1024 + sgrp * 8;
  char* ldsDst = (char*)lds + tid * 16;

#define ST_A0(kt) do { const u16* s_ = Ag + (kt) * 64;           char* d_ = ldsDst + (((kt) & 1) * 49152);         gl2lds16(s_, d_); gl2lds16(s_ + 65536, d_ + 8192); } while (0)
#define ST_A1(kt) do { const u16* s_ = Ag + 131072 + (kt) * 64;  char* d_ = ldsDst + (((kt) & 1) * 49152) + 16384; gl2lds16(s_, d_); gl2lds16(s_ + 65536, d_ + 8192); } while (0)
#define ST_B(kt)  do { const u16* s_ = Bg + (kt) * 64;           char* d_ = ldsDst + (((kt) & 1) * 49152) + 32768; gl2lds16(s_, d_); gl2lds16(s_ + 65536, d_ + 8192); } while (0)

  // Prologue: K-tile 0 complete + A0/B of K-tile 1 (A1(1) staged at Q1).
  ST_A0(0); ST_B(0); ST_A1(0);
  ST_A0(1); ST_B(1);

  const int lane = tid & 63, wid = tid >> 6;
  const int wr = wid >> 2, wc = wid & 3;
  const int l15 = lane & 15, quad = lane >> 4;

  int aoff[4][2], boff[2][2];
#pragma unroll
  for (int i_ = 0; i_ < 4; ++i_) {
    const int arow = wr * 64 + i_ * 16 + l15;
#pragma unroll
    for (int k_ = 0; k_ < 2; ++k_)
      aoff[i_][k_] = arow * 64 + ((k_ * 4 + quad + arow) & 7) * 8;
  }
#pragma unroll
  for (int j_ = 0; j_ < 2; ++j_) {
    const int brow = wc * 32 + j_ * 16 + l15;
#pragma unroll
    for (int k_ = 0; k_ < 2; ++k_)
      boff[j_][k_] = brow * 64 + ((k_ * 4 + quad + brow) & 7) * 8;
  }

  f32x4 acc[2][4][2];
#pragma unroll
  for (int q_ = 0; q_ < 2; ++q_)
#pragma unroll
    for (int i_ = 0; i_ < 4; ++i_)
#pragma unroll
      for (int j_ = 0; j_ < 2; ++j_)
        acc[q_][i_][j_] = (f32x4){0.f, 0.f, 0.f, 0.f};

  bf16x8 af[4][2], bfr[2][2];

#define SLOADA(qm, buf) do { const u16* p_ = lds + (buf) * 24576 + (qm) * 8192; \
  _Pragma("unroll") for (int i_ = 0; i_ < 4; ++i_) \
  _Pragma("unroll") for (int k_ = 0; k_ < 2; ++k_) \
    af[i_][k_] = *(const bf16x8*)(p_ + aoff[i_][k_]); } while (0)
#define SLOADB(buf) do { const u16* p_ = lds + (buf) * 24576 + 16384; \
  _Pragma("unroll") for (int j_ = 0; j_ < 2; ++j_) \
  _Pragma("unroll") for (int k_ = 0; k_ < 2; ++k_) \
    bfr[j_][k_] = *(const bf16x8*)(p_ + boff[j_][k_]); } while (0)
#define SMMA(qm) do { \
  _Pragma("unroll") for (int i_ = 0; i_ < 4; ++i_) \
  _Pragma("unroll") for (int j_ = 0; j_ < 2; ++j_) \
  _Pragma("unroll") for (int k_ = 0; k_ < 2; ++k_) \
    acc[qm][i_][j_] = __builtin_amdgcn_mfma_f32_16x16x32_bf16( \
        af[i_][k_], bfr[j_][k_], acc[qm][i_][j_], 0, 0, 0); } while (0)

#define BAR __builtin_amdgcn_s_barrier()
#define WLG0 asm volatile("s_waitcnt lgkmcnt(0)")
#define PRIO1 __builtin_amdgcn_s_setprio(1)
#define PRIO0 __builtin_amdgcn_s_setprio(0)
#define WVM4 asm volatile("s_waitcnt vmcnt(4)" ::: "memory")
#define WVM0 asm volatile("s_waitcnt vmcnt(0)" ::: "memory")

  WVM4;  // K-tile 0 (3 STs) landed
  BAR;

#pragma unroll 1
  for (int it = 0; it < 7; ++it) {
    const int j0 = 2 * it;
    // Q1 (K-tile j0, qm=0) — read-ahead af(1) for Q2
    SLOADA(0, 0); SLOADB(0); ST_A1(j0 + 1);
    BAR; WLG0; PRIO1; SMMA(0); PRIO0; SLOADA(1, 0); BAR;
    // Q2 (j0, qm=1)
    ST_A0(j0 + 2); ST_B(j0 + 2);
    BAR; WLG0; PRIO1; SMMA(1); PRIO0;
    WVM4;  // K-tile j0+1 landed
    BAR;
    // Q3 (j0+1, qm=0)
    SLOADA(0, 1); SLOADB(1); ST_A1(j0 + 2);
    BAR; WLG0; PRIO1; SMMA(0); PRIO0; SLOADA(1, 1); BAR;
    // Q4 (j0+1, qm=1)
    ST_A0(j0 + 3); ST_B(j0 + 3);
    BAR; WLG0; PRIO1; SMMA(1); PRIO0;
    WVM4;  // K-tile j0+2 landed
    BAR;
  }
  {  // tail: K-tiles 14, 15
    SLOADA(0, 0); SLOADB(0); ST_A1(15);
    BAR; WLG0; PRIO1; SMMA(0); PRIO0; SLOADA(1, 0); BAR;
    BAR; WLG0; PRIO1; SMMA(1); PRIO0;
    WVM0;  // drain (K-tile 15 complete)
    BAR;
    SLOADA(0, 1); SLOADB(1);
    BAR; WLG0; PRIO1; SMMA(0); PRIO0; SLOADA(1, 1); BAR;
    BAR; WLG0; PRIO1; SMMA(1); PRIO0; BAR;
  }

  // Epilogue: exp/mask, row sums (over s) -> atomicAdd, stage [t][s] 128x256
  // (stride 264) in LDS, store to the packed triangular strip.
  const int moff = (rt & 1) * 128;  // diag shift: mask if s_loc > t_loc + moff
  float sj[2] = {0.f, 0.f};
#pragma unroll
  for (int qm = 0; qm < 2; ++qm)
#pragma unroll
    for (int i_ = 0; i_ < 4; ++i_) {
      const int s0 = qm * 128 + wr * 64 + i_ * 16 + quad * 4;
#pragma unroll
      for (int j_ = 0; j_ < 2; ++j_) {
        const int t = wc * 32 + j_ * 16 + l15;
        ushort4 o;
        float e[4];
#pragma unroll
        for (int r = 0; r < 4; ++r) {
          float v = __expf(acc[qm][i_][j_][r] * 0.03125f);
          if (maskT && (s0 + r) > (t + moff)) v = 0.f;
          e[r] = v;
          sj[j_] += v;
        }
        o.x = f32_to_bf16(e[0]);
        o.y = f32_to_bf16(e[1]);
        o.z = f32_to_bf16(e[2]);
        o.w = f32_to_bf16(e[3]);
        *(ushort4*)(lds + t * 264 + s0) = o;
      }
    }
#pragma unroll
  for (int j_ = 0; j_ < 2; ++j_) {
    float v = sj[j_];
    v += __shfl_xor(v, 16);
    v += __shfl_xor(v, 32);
    if (quad == 0)
      atomicAdd(&sums[(size_t)b * 2048 + rt * 128 + wc * 32 + j_ * 16 + l15], v);
  }
  __syncthreads();
  const int ld = (rt + 1) * 128;
  const int nc = ld - ct * 256;  // 256 normally; 128 on even-rt last tile
  u16* Out = Spk + (size_t)b * S_BATCH + (size_t)(rt * (rt + 1) / 2) * 16384 +
             ct * 256;
  if (nc >= 256) {
#pragma unroll
    for (int p = 0; p < 8; ++p) {
      const int row = p * 16 + (tid >> 5);
      const int c0 = (tid & 31) * 8;
      const uint4 v = *(const uint4*)(lds + row * 264 + c0);
      *(uint4*)(Out + (size_t)row * ld + c0) = v;
    }
  } else {
#pragma unroll
    for (int p = 0; p < 4; ++p) {
      const int row = p * 32 + (tid >> 4);
      const int c0 = (tid & 15) * 8;
      const uint4 v = *(const uint4*)(lds + row * 264 + c0);
      *(uint4*)(Out + (size_t)row * ld + c0) = v;
    }
  }
#undef ST_A0
#undef ST_A1
#undef ST_B
#undef SLOADA
#undef SLOADB
#undef SMMA
#undef BAR
#undef WLG0
#undef PRIO1
#undef PRIO0
#undef WVM4
#undef WVM0
}

// ---------------------------------------------------------------------------
// out[b][t][c] = (1/sums[b][t]) * sum_s S[b][t][s] * Vt[b][c][s].
__global__ __launch_bounds__(256) void pv_kernel(const u16* __restrict__ Spk,
                                                 const u16* __restrict__ Vt,
                                                 const float* __restrict__ sums,
                                                 float* __restrict__ Out) {
  const int b = blockIdx.x & 7;
  const int local = 127 - (blockIdx.x >> 3);  // 0..127 descending work
  const int rt = local >> 3;
  const int ct = local & 7;

  __shared__ __align__(16) u16 smem[SMEM_U16];
  u16* As = smem;
  u16* Bs = smem + 8192;
  float* ftile = (float*)smem;  // 64(t) x 132(c) fp32 = 33792B

  f32x4 acc[4][4];
#pragma unroll
  for (int i = 0; i < 4; ++i)
#pragma unroll
    for (int j = 0; j < 4; ++j) acc[i][j] = (f32x4){0.f, 0.f, 0.f, 0.f};

  const u16* A = Vt + ((size_t)b * 1024 + ct * 128) * 2048;  // rows = c
  const u16* B = Spk + (size_t)b * S_BATCH +
                 (size_t)(rt * (rt + 1) / 2) * 16384;        // rows = t
  const int ldb = (rt + 1) * 128;
  gemm_bt_mainloop(A, B, 2048, ldb, (rt + 1) * 2, As, Bs, acc);

  const int tid = threadIdx.x;
  const int lane = tid & 63, wid = tid >> 6;
  const int wr = wid >> 1, wc = wid & 1;
  const int l15 = lane & 15, quad = lane >> 4;

  const float* sumsb = sums + (size_t)b * 2048 + rt * 128;
  float* Ob = Out + (size_t)b * 2048 * 1024 + (size_t)(rt * 128) * 1024 +
              ct * 128;
#pragma unroll
  for (int h = 0; h < 2; ++h) {   // t-halves by wc
    if (wc == h) {
#pragma unroll
      for (int j = 0; j < 4; ++j) {
        const int tl = j * 16 + l15;                  // t within half
        const float iv = 1.0f / sumsb[h * 64 + tl];
#pragma unroll
        for (int i = 0; i < 4; ++i) {
          const int c0 = wr * 64 + i * 16 + quad * 4;
          float4 v;
          v.x = acc[i][j][0] * iv;
          v.y = acc[i][j][1] * iv;
          v.z = acc[i][j][2] * iv;
          v.w = acc[i][j][3] * iv;
          *(float4*)(ftile + tl * 132 + c0) = v;
        }
      }
    }
    __syncthreads();
#pragma unroll
    for (int rr = 0; rr < 8; ++rr) {
      const int row = rr * 8 + (tid >> 5);        // 8 rows/iter x 8 = 64 rows
      const int c0 = (tid & 31) * 4;              // 32 lanes x 4 f32 = 128 col
      const float4 v = *(const float4*)(ftile + row * 132 + c0);
      *(float4*)(Ob + (size_t)(h * 64 + row) * 1024 + c0) = v;
    }
    __syncthreads();
  }
}

// ---------------------------------------------------------------------------
extern "C" void kernel_launch(void* const* d_in, const int* in_sizes, int n_in,
                              void* d_out, int out_size, void* d_ws,
                              size_t ws_size, hipStream_t stream) {
  const float* x = (const float*)d_in[0];
  const float* wq = (const float*)d_in[1];
  const float* bq = (const float*)d_in[2];
  const float* wk = (const float*)d_in[3];
  const float* bk = (const float*)d_in[4];
  const float* wv = (const float*)d_in[5];
  const float* bv = (const float*)d_in[6];
  float* out = (float*)d_out;
  char* ws = (char*)d_ws;

  // Workspace layout (<=160 MB):
  //   [0,32M)      Qb bf16 [16384][1024]
  //   [32,64M)     Kb bf16 [16384][1024]
  //   [64,96M)     Vt bf16 [8][1024][2048]
  //   [96,130.1M)  Spk bf16 packed triangular [8][136*16384]
  //   [132,132.07M) sums fp32 [16384]
  //   [134,140M)   wb bf16 [3][1024][1024]
  //   xb (32MB @96M) aliases Spk: dead after qkv pass.
  u16* Qb = (u16*)(ws);
  u16* Kb = (u16*)(ws + ((size_t)32 << 20));
  u16* Vt = (u16*)(ws + ((size_t)64 << 20));
  u16* Spk = (u16*)(ws + ((size_t)96 << 20));
  u16* xb = (u16*)(ws + ((size_t)96 << 20));   // alias: dies before Spk written
  float* sums = (float*)(ws + ((size_t)132 << 20));
  u16* wb = (u16*)(ws + ((size_t)134 << 20));

  // pass 0: casts + sums zero-init
  cast_f32_to_bf16_kernel<<<16384, 256, 0, stream>>>(x, xb, 16777216 / 4);
  cast_w_kernel<<<dim3(512, 4), 256, 0, stream>>>(wq, wk, wv, wb, sums);

  // pass 1: fused Q,K,V projections (V transposed), 256^2 8-phase read-ahead
  qkv_kernel<<<768, 512, 0, stream>>>(xb, wb, bq, bk, bv, Qb, Kb, Vt);

  // pass 2: causal exp-scores, 256x128-tile 8-phase (packed layout unchanged)
  score_kernel<<<576, 512, 0, stream>>>(Kb, Qb, Spk, sums);

  // pass 3: P @ V scaled by 1/sums
  pv_kernel<<<8 * 128, 256, 0, stream>>>(Spk, Vt, sums, out);
}

// Round 3
// 331.805 us; speedup vs baseline: 1.0343x; 1.0044x over previous
//
#include <hip/hip_runtime.h>
#include <stdint.h>

typedef unsigned short u16;
typedef __attribute__((ext_vector_type(8))) __bf16 bf16x8;
typedef __attribute__((ext_vector_type(4))) float f32x4;

#define DEVI __device__ __forceinline__

DEVI u16 f32_to_bf16(float f) {
  uint32_t u = __builtin_bit_cast(uint32_t, f);
  u += 0x7FFFu + ((u >> 16) & 1u);   // RNE; inputs are never NaN here
  return (u16)(u >> 16);
}

DEVI void gl2lds16(const void* g, void* l) {
  __builtin_amdgcn_global_load_lds(
      (const __attribute__((address_space(1))) void*)g,
      (__attribute__((address_space(3))) void*)l, 16, 0, 0);
}

// S is packed triangular: per batch, strip rt (128 rows) has row stride
// (rt+1)*128 and begins at tri(rt)*16384 u16.  Per-batch size 136*16384 u16.
#define S_BATCH 2228224  // u16 elements per batch = 136*16384

// ---------------------------------------------------------------------------
__global__ void cast_f32_to_bf16_kernel(const float* __restrict__ src,
                                        u16* __restrict__ dst, int n4) {
  int i = blockIdx.x * blockDim.x + threadIdx.x;
  const int stride = gridDim.x * blockDim.x;
  for (; i < n4; i += stride) {
    const float4 v = ((const float4*)src)[i];
    ushort4 o;
    o.x = f32_to_bf16(v.x);
    o.y = f32_to_bf16(v.y);
    o.z = f32_to_bf16(v.z);
    o.w = f32_to_bf16(v.w);
    ((ushort4*)dst)[i] = o;
  }
}

// weights -> contiguous bf16 [3][1024][1024]; z==3 zero-inits sums[16384].
__global__ void cast_w_kernel(const float* __restrict__ wq,
                              const float* __restrict__ wk,
                              const float* __restrict__ wv,
                              u16* __restrict__ wb, float* __restrict__ sums) {
  const int z = blockIdx.y;
  if (z == 3) {
    int i = blockIdx.x * blockDim.x + threadIdx.x;
    if (i < 4096) ((float4*)sums)[i] = (float4){0.f, 0.f, 0.f, 0.f};
    return;
  }
  const float* src = (z == 0) ? wq : (z == 1) ? wk : wv;
  u16* dst = wb + (size_t)z * 1048576;
  int i = blockIdx.x * blockDim.x + threadIdx.x;
  const int stride = gridDim.x * blockDim.x;
  for (; i < 262144; i += stride) {
    const float4 v = ((const float4*)src)[i];
    ushort4 o;
    o.x = f32_to_bf16(v.x);
    o.y = f32_to_bf16(v.y);
    o.z = f32_to_bf16(v.z);
    o.w = f32_to_bf16(v.w);
    ((ushort4*)dst)[i] = o;
  }
}

// ---------------------------------------------------------------------------
// Fused Q/K/V projection — 256x256-tile, 8-wave, 8-phase schedule (T3+T4+T5).
// Phase-head load placement (A/B-verified: beats MFMA-tail read-ahead by 9%).
//
// GEMM: C[m][n] += sum_k A[m][k]*B[n][k], M=N=256, K=1024 (16 K-tiles of 64).
// Waves: wr=wid>>2 (2 M-groups), wc=wid&3 (4 N-groups).  Fragment (qm,qn,i,j):
//   m = qm*128 + wr*64 + i*16 + quad*4 + r   (i=0..3)
//   n = qn*128 + wc*32 + j*16 + l15          (j=0..1)
// LDS 128KB: 2 bufs x {A0,A1,B0,B1} 16KB regions; row stride 64 u16, per-row
// rotated column groups (conflict-free, gl_lds-linear).
// vmcnt(6) = 3 half-tiles in flight lands exactly the next K-tile at P4/P8.
// ---------------------------------------------------------------------------
__global__ __launch_bounds__(512, 2) void qkv_kernel(
    const u16* __restrict__ xb, const u16* __restrict__ wb,
    const float* __restrict__ bq, const float* __restrict__ bk,
    const float* __restrict__ bv, u16* __restrict__ Qb, u16* __restrict__ Kb,
    u16* __restrict__ Vt) {
  __shared__ __align__(16) u16 lds[65536];  // 128 KB

  const int id = blockIdx.x;                 // 0..767
  const int wg = (id & 7) * 96 + (id >> 3);  // bijective XCD swizzle (768%8==0)
  const int g = wg >> 3, u = wg & 7;         // groups of 8 tiles: 4c x 2t (~3MB L2)
  const int z = g >> 5;                      // 0..2
  const int tp = g & 31;                     // t-pair
  const int tmt = tp * 2 + (u >> 2);         // t-tile 0..63
  const int tct = u & 3;                     // c-tile 0..3

  // Q/K: A=W (m=c, reg-quad packs c); V: A=x (m=t, reg-quad packs t).
  int m0, n0;
  const u16* Aptr;
  const u16* Bptr;
  if (z < 2) {
    m0 = tct * 256;
    n0 = tmt * 256;
    Aptr = wb + (size_t)z * 1048576 + (size_t)m0 * 1024;
    Bptr = xb + (size_t)n0 * 1024;
  } else {
    m0 = tmt * 256;
    n0 = tct * 256;
    Aptr = xb + (size_t)m0 * 1024;
    Bptr = wb + (size_t)2 * 1048576 + (size_t)n0 * 1024;
  }

  const int tid = threadIdx.x;
  const int srow = tid >> 3;                 // staged row 0..63 (+64 2nd load)
  const int sgrp = ((tid & 7) - srow) & 7;   // rotated source column-group
  const u16* Ag = Aptr + (size_t)srow * 1024 + sgrp * 8;
  const u16* Bg = Bptr + (size_t)srow * 1024 + sgrp * 8;
  char* ldsDst = (char*)lds + tid * 16;

  // Half-tile stagers: 2 x gl_lds x 16B per thread = 128 rows x 64 cols bf16.
#define ST_A0(kt) do { const u16* s_ = Ag + (kt) * 64;           char* d_ = ldsDst + (((kt) & 1) * 65536);         gl2lds16(s_, d_); gl2lds16(s_ + 65536, d_ + 8192); } while (0)
#define ST_A1(kt) do { const u16* s_ = Ag + 131072 + (kt) * 64;  char* d_ = ldsDst + (((kt) & 1) * 65536) + 16384; gl2lds16(s_, d_); gl2lds16(s_ + 65536, d_ + 8192); } while (0)
#define ST_B0(kt) do { const u16* s_ = Bg + (kt) * 64;           char* d_ = ldsDst + (((kt) & 1) * 65536) + 32768; gl2lds16(s_, d_); gl2lds16(s_ + 65536, d_ + 8192); } while (0)
#define ST_B1(kt) do { const u16* s_ = Bg + 131072 + (kt) * 64;  char* d_ = ldsDst + (((kt) & 1) * 65536) + 49152; gl2lds16(s_, d_); gl2lds16(s_ + 65536, d_ + 8192); } while (0)

  // Prologue: K-tile 0 complete + A0/B0/B1 of K-tile 1 (7 half-tiles).
  ST_A0(0); ST_B0(0); ST_B1(0); ST_A1(0);
  ST_A0(1); ST_B0(1); ST_B1(1);

  const int lane = tid & 63, wid = tid >> 6;
  const int wr = wid >> 2, wc = wid & 3;
  const int l15 = lane & 15, quad = lane >> 4;

  int aoff[4][2], boff[2][2];
#pragma unroll
  for (int i_ = 0; i_ < 4; ++i_) {
    const int arow = wr * 64 + i_ * 16 + l15;
#pragma unroll
    for (int k_ = 0; k_ < 2; ++k_)
      aoff[i_][k_] = arow * 64 + ((k_ * 4 + quad + arow) & 7) * 8;
  }
#pragma unroll
  for (int j_ = 0; j_ < 2; ++j_) {
    const int brow = wc * 32 + j_ * 16 + l15;
#pragma unroll
    for (int k_ = 0; k_ < 2; ++k_)
      boff[j_][k_] = brow * 64 + ((k_ * 4 + quad + brow) & 7) * 8;
  }

  f32x4 acc[2][2][4][2];
#pragma unroll
  for (int a_ = 0; a_ < 2; ++a_)
#pragma unroll
    for (int b_ = 0; b_ < 2; ++b_)
#pragma unroll
      for (int i_ = 0; i_ < 4; ++i_)
#pragma unroll
        for (int j_ = 0; j_ < 2; ++j_)
          acc[a_][b_][i_][j_] = (f32x4){0.f, 0.f, 0.f, 0.f};

  bf16x8 af[4][2], bfr[2][2][2];

#define LOADA(qm, buf) do { const u16* p_ = lds + (buf) * 32768 + (qm) * 8192; \
  _Pragma("unroll") for (int i_ = 0; i_ < 4; ++i_) \
  _Pragma("unroll") for (int k_ = 0; k_ < 2; ++k_) \
    af[i_][k_] = *(const bf16x8*)(p_ + aoff[i_][k_]); } while (0)
#define LOADB(qn, buf) do { const u16* p_ = lds + (buf) * 32768 + 16384 + (qn) * 8192; \
  _Pragma("unroll") for (int j_ = 0; j_ < 2; ++j_) \
  _Pragma("unroll") for (int k_ = 0; k_ < 2; ++k_) \
    bfr[qn][j_][k_] = *(const bf16x8*)(p_ + boff[j_][k_]); } while (0)
#define MMA(qm, qn) do { \
  _Pragma("unroll") for (int i_ = 0; i_ < 4; ++i_) \
  _Pragma("unroll") for (int j_ = 0; j_ < 2; ++j_) \
  _Pragma("unroll") for (int k_ = 0; k_ < 2; ++k_) \
    acc[qm][qn][i_][j_] = __builtin_amdgcn_mfma_f32_16x16x32_bf16( \
        af[i_][k_], bfr[qn][j_][k_], acc[qm][qn][i_][j_], 0, 0, 0); } while (0)

#define BAR __builtin_amdgcn_s_barrier()
#define WLG0 asm volatile("s_waitcnt lgkmcnt(0)")
#define WLG8 asm volatile("s_waitcnt lgkmcnt(8)")
#define PRIO1 __builtin_amdgcn_s_setprio(1)
#define PRIO0 __builtin_amdgcn_s_setprio(0)
#define WVM6 asm volatile("s_waitcnt vmcnt(6)" ::: "memory")
#define WVM0 asm volatile("s_waitcnt vmcnt(0)" ::: "memory")

  WVM6;  // K-tile 0 landed
  BAR;

#pragma unroll 1
  for (int it = 0; it < 7; ++it) {
    const int j0 = 2 * it;
    // P1 (0,0) buf0
    LOADA(0, 0); LOADB(0, 0); ST_A1(j0 + 1); WLG8;
    BAR; WLG0; PRIO1; MMA(0, 0); PRIO0; BAR;
    // P2 (0,1)
    LOADB(1, 0); ST_A0(j0 + 2);
    BAR; WLG0; PRIO1; MMA(0, 1); PRIO0; BAR;
    // P3 (1,1)
    LOADA(1, 0); ST_B0(j0 + 2);
    BAR; WLG0; PRIO1; MMA(1, 1); PRIO0; BAR;
    // P4 (1,0)
    ST_B1(j0 + 2);
    BAR; PRIO1; MMA(1, 0); PRIO0;
    WVM6;  // K-tile j0+1 landed
    BAR;
    // P5 (0,0) buf1
    LOADA(0, 1); LOADB(0, 1); ST_A1(j0 + 2); WLG8;
    BAR; WLG0; PRIO1; MMA(0, 0); PRIO0; BAR;
    // P6 (0,1)
    LOADB(1, 1); ST_A0(j0 + 3);
    BAR; WLG0; PRIO1; MMA(0, 1); PRIO0; BAR;
    // P7 (1,1)
    LOADA(1, 1); ST_B0(j0 + 3);
    BAR; WLG0; PRIO1; MMA(1, 1); PRIO0; BAR;
    // P8 (1,0)
    ST_B1(j0 + 3);
    BAR; PRIO1; MMA(1, 0); PRIO0;
    WVM6;  // K-tile j0+2 landed
    BAR;
  }
  {  // it = 7: K-tiles 14 (buf0) / 15 (buf1); only A1(15) left to stage
    LOADA(0, 0); LOADB(0, 0); ST_A1(15); WLG8;
    BAR; WLG0; PRIO1; MMA(0, 0); PRIO0; BAR;
    LOADB(1, 0);
    BAR; WLG0; PRIO1; MMA(0, 1); PRIO0; BAR;
    LOADA(1, 0);
    BAR; WLG0; PRIO1; MMA(1, 1); PRIO0; BAR;
    BAR; PRIO1; MMA(1, 0); PRIO0;
    WVM0;  // drain: K-tile 15 landed
    BAR;
    LOADA(0, 1); LOADB(0, 1); WLG8;
    BAR; WLG0; PRIO1; MMA(0, 0); PRIO0; BAR;
    LOADB(1, 1);
    BAR; WLG0; PRIO1; MMA(0, 1); PRIO0; BAR;
    LOADA(1, 1);
    BAR; WLG0; PRIO1; MMA(1, 1); PRIO0; BAR;
    PRIO1; MMA(1, 0); PRIO0;
    BAR;  // mainloop done; LDS reusable
  }

  // Epilogue: per N-half th, stage [128 n-rows][256 m-cols] (+8 pad) in LDS,
  // then full-line 16B/lane global stores.
  if (z < 2) {
    const float* bias = (z == 0) ? bq : bk;
    u16* Out = (z == 0) ? Qb : Kb;
#pragma unroll
    for (int th = 0; th < 2; ++th) {
      if (th) __syncthreads();
#pragma unroll
      for (int qm = 0; qm < 2; ++qm)
#pragma unroll
        for (int i_ = 0; i_ < 4; ++i_) {
          const int c = qm * 128 + wr * 64 + i_ * 16 + quad * 4;
          const float4 b4 = *(const float4*)(bias + m0 + c);
#pragma unroll
          for (int j_ = 0; j_ < 2; ++j_) {
            const int row = wc * 32 + j_ * 16 + l15;
            ushort4 o;
            o.x = f32_to_bf16(acc[qm][th][i_][j_][0] + b4.x);
            o.y = f32_to_bf16(acc[qm][th][i_][j_][1] + b4.y);
            o.z = f32_to_bf16(acc[qm][th][i_][j_][2] + b4.z);
            o.w = f32_to_bf16(acc[qm][th][i_][j_][3] + b4.w);
            *(ushort4*)(lds + row * 264 + c) = o;   // [t][c]
          }
        }
      __syncthreads();
#pragma unroll
      for (int p = 0; p < 8; ++p) {
        const int row = p * 16 + (tid >> 5);
        const int c0 = (tid & 31) * 8;
        const uint4 v = *(const uint4*)(lds + row * 264 + c0);
        *(uint4*)(Out + (size_t)(n0 + th * 128 + row) * 1024 + m0 + c0) = v;
      }
    }
  } else {
    const int b = m0 >> 11;
    const int t0b = m0 & 2047;
    u16* Out = Vt + (size_t)b * 2097152;
#pragma unroll
    for (int th = 0; th < 2; ++th) {
      if (th) __syncthreads();
#pragma unroll
      for (int j_ = 0; j_ < 2; ++j_) {
        const int row = wc * 32 + j_ * 16 + l15;      // c within half
        const float bb = bv[n0 + th * 128 + row];
#pragma unroll
        for (int qm = 0; qm < 2; ++qm)
#pragma unroll
          for (int i_ = 0; i_ < 4; ++i_) {
            const int c = qm * 128 + wr * 64 + i_ * 16 + quad * 4;  // t
            ushort4 o;
            o.x = f32_to_bf16(acc[qm][th][i_][j_][0] + bb);
            o.y = f32_to_bf16(acc[qm][th][i_][j_][1] + bb);
            o.z = f32_to_bf16(acc[qm][th][i_][j_][2] + bb);
            o.w = f32_to_bf16(acc[qm][th][i_][j_][3] + bb);
            *(ushort4*)(lds + row * 264 + c) = o;     // [c][t]
          }
      }
      __syncthreads();
#pragma unroll
      for (int p = 0; p < 8; ++p) {
        const int row = p * 16 + (tid >> 5);
        const int c0 = (tid & 31) * 8;
        const uint4 v = *(const uint4*)(lds + row * 264 + c0);
        *(uint4*)(Out + (size_t)(n0 + th * 128 + row) * 2048 + t0b + c0) = v;
      }
    }
  }
#undef ST_A0
#undef ST_A1
#undef ST_B0
#undef ST_B1
#undef LOADA
#undef LOADB
#undef MMA
#undef BAR
#undef WLG0
#undef WLG8
#undef PRIO1
#undef PRIO0
#undef WVM6
#undef WVM0
}

// ---------------------------------------------------------------------------
// Scores — 256(s) x 128(t) tile, 8 waves, 2 phases/K-tile, phase-head loads.
// S[b][t][s] = exp((K.Q)/32), causal-masked, packed triangular.
// Fragment: s = qm*128 + wr*64 + i*16 + quad*4 + r ; t = wc*32 + j*16 + l15.
// LDS 96KB: 2 bufs x {A0,A1,B} x 16KB (row stride 64 u16, rotated groups).
// Grid 576 = 8 batches (one per XCD) x 72 tiles; all tiles equal cost.
// ---------------------------------------------------------------------------
__global__ __launch_bounds__(512, 2) void score_kernel(const u16* __restrict__ Kb,
                                                       const u16* __restrict__ Qb,
                                                       u16* __restrict__ Spk,
                                                       float* __restrict__ sums) {
  __shared__ __align__(16) u16 lds[49152];  // 96 KB

  const int id = blockIdx.x;   // 0..575
  const int b = id & 7;        // batch per XCD: K/Q tiles stay in XCD L2
  const int l = id >> 3;       // 0..71
  int k = (int)((sqrtf(4.f * l + 1.f) - 1.f) * 0.5f);
  if (k * (k + 1) > l) --k;
  if ((k + 1) * (k + 2) <= l) ++k;
  const int off = l - k * (k + 1);
  const int hi = (off >= (k + 1));
  const int rt = 2 * k + hi;           // t-strip 0..15 (128 rows)
  const int ct = off - (hi ? (k + 1) : 0);  // s-tile 0..k (256 cols)
  const bool maskT = (ct == k);        // only the last s-tile crosses diag

  const int tid = threadIdx.x;
  const int srow = tid >> 3;
  const int sgrp = ((tid & 7) - srow) & 7;
  const u16* A = Qb + ((size_t)b * 2048 + ct * 256) * 1024;  // 256 s-rows
  const u16* B = Kb + ((size_t)b * 2048 + rt * 128) * 1024;  // 128 t-rows
  const u16* Ag = A + (size_t)srow * 1024 + sgrp * 8;
  const u16* Bg = B + (size_t)srow * 1024 + sgrp * 8;
  char* ldsDst = (char*)lds + tid * 16;

#define ST_A0(kt) do { const u16* s_ = Ag + (kt) * 64;           char* d_ = ldsDst + (((kt) & 1) * 49152);         gl2lds16(s_, d_); gl2lds16(s_ + 65536, d_ + 8192); } while (0)
#define ST_A1(kt) do { const u16* s_ = Ag + 131072 + (kt) * 64;  char* d_ = ldsDst + (((kt) & 1) * 49152) + 16384; gl2lds16(s_, d_); gl2lds16(s_ + 65536, d_ + 8192); } while (0)
#define ST_B(kt)  do { const u16* s_ = Bg + (kt) * 64;           char* d_ = ldsDst + (((kt) & 1) * 49152) + 32768; gl2lds16(s_, d_); gl2lds16(s_ + 65536, d_ + 8192); } while (0)

  // Prologue: K-tile 0 complete + A0/B of K-tile 1 (A1(1) staged at Q1).
  ST_A0(0); ST_B(0); ST_A1(0);
  ST_A0(1); ST_B(1);

  const int lane = tid & 63, wid = tid >> 6;
  const int wr = wid >> 2, wc = wid & 3;
  const int l15 = lane & 15, quad = lane >> 4;

  int aoff[4][2], boff[2][2];
#pragma unroll
  for (int i_ = 0; i_ < 4; ++i_) {
    const int arow = wr * 64 + i_ * 16 + l15;
#pragma unroll
    for (int k_ = 0; k_ < 2; ++k_)
      aoff[i_][k_] = arow * 64 + ((k_ * 4 + quad + arow) & 7) * 8;
  }
#pragma unroll
  for (int j_ = 0; j_ < 2; ++j_) {
    const int brow = wc * 32 + j_ * 16 + l15;
#pragma unroll
    for (int k_ = 0; k_ < 2; ++k_)
      boff[j_][k_] = brow * 64 + ((k_ * 4 + quad + brow) & 7) * 8;
  }

  f32x4 acc[2][4][2];
#pragma unroll
  for (int q_ = 0; q_ < 2; ++q_)
#pragma unroll
    for (int i_ = 0; i_ < 4; ++i_)
#pragma unroll
      for (int j_ = 0; j_ < 2; ++j_)
        acc[q_][i_][j_] = (f32x4){0.f, 0.f, 0.f, 0.f};

  bf16x8 af[4][2], bfr[2][2];

#define SLOADA(qm, buf) do { const u16* p_ = lds + (buf) * 24576 + (qm) * 8192; \
  _Pragma("unroll") for (int i_ = 0; i_ < 4; ++i_) \
  _Pragma("unroll") for (int k_ = 0; k_ < 2; ++k_) \
    af[i_][k_] = *(const bf16x8*)(p_ + aoff[i_][k_]); } while (0)
#define SLOADB(buf) do { const u16* p_ = lds + (buf) * 24576 + 16384; \
  _Pragma("unroll") for (int j_ = 0; j_ < 2; ++j_) \
  _Pragma("unroll") for (int k_ = 0; k_ < 2; ++k_) \
    bfr[j_][k_] = *(const bf16x8*)(p_ + boff[j_][k_]); } while (0)
#define SMMA(qm) do { \
  _Pragma("unroll") for (int i_ = 0; i_ < 4; ++i_) \
  _Pragma("unroll") for (int j_ = 0; j_ < 2; ++j_) \
  _Pragma("unroll") for (int k_ = 0; k_ < 2; ++k_) \
    acc[qm][i_][j_] = __builtin_amdgcn_mfma_f32_16x16x32_bf16( \
        af[i_][k_], bfr[j_][k_], acc[qm][i_][j_], 0, 0, 0); } while (0)

#define BAR __builtin_amdgcn_s_barrier()
#define WLG0 asm volatile("s_waitcnt lgkmcnt(0)")
#define PRIO1 __builtin_amdgcn_s_setprio(1)
#define PRIO0 __builtin_amdgcn_s_setprio(0)
#define WVM4 asm volatile("s_waitcnt vmcnt(4)" ::: "memory")
#define WVM0 asm volatile("s_waitcnt vmcnt(0)" ::: "memory")

  WVM4;  // K-tile 0 (3 STs) landed
  BAR;

#pragma unroll 1
  for (int it = 0; it < 7; ++it) {
    const int j0 = 2 * it;
    // Q1 (K-tile j0, qm=0)
    SLOADA(0, 0); SLOADB(0); ST_A1(j0 + 1);
    BAR; WLG0; PRIO1; SMMA(0); PRIO0; BAR;
    // Q2 (j0, qm=1)
    SLOADA(1, 0); ST_A0(j0 + 2); ST_B(j0 + 2);
    BAR; WLG0; PRIO1; SMMA(1); PRIO0;
    WVM4;  // K-tile j0+1 landed
    BAR;
    // Q3 (j0+1, qm=0)
    SLOADA(0, 1); SLOADB(1); ST_A1(j0 + 2);
    BAR; WLG0; PRIO1; SMMA(0); PRIO0; BAR;
    // Q4 (j0+1, qm=1)
    SLOADA(1, 1); ST_A0(j0 + 3); ST_B(j0 + 3);
    BAR; WLG0; PRIO1; SMMA(1); PRIO0;
    WVM4;  // K-tile j0+2 landed
    BAR;
  }
  {  // tail: K-tiles 14, 15
    SLOADA(0, 0); SLOADB(0); ST_A1(15);
    BAR; WLG0; PRIO1; SMMA(0); PRIO0; BAR;
    SLOADA(1, 0);
    BAR; WLG0; PRIO1; SMMA(1); PRIO0;
    WVM0;  // drain (K-tile 15 complete)
    BAR;
    SLOADA(0, 1); SLOADB(1);
    BAR; WLG0; PRIO1; SMMA(0); PRIO0; BAR;
    SLOADA(1, 1);
    BAR; WLG0; PRIO1; SMMA(1); PRIO0; BAR;
  }

  // Epilogue: exp/mask, row sums (over s) -> atomicAdd, stage [t][s] 128x256
  // (stride 264) in LDS, store to the packed triangular strip.
  const int moff = (rt & 1) * 128;  // diag shift: mask if s_loc > t_loc + moff
  float sj[2] = {0.f, 0.f};
#pragma unroll
  for (int qm = 0; qm < 2; ++qm)
#pragma unroll
    for (int i_ = 0; i_ < 4; ++i_) {
      const int s0 = qm * 128 + wr * 64 + i_ * 16 + quad * 4;
#pragma unroll
      for (int j_ = 0; j_ < 2; ++j_) {
        const int t = wc * 32 + j_ * 16 + l15;
        ushort4 o;
        float e[4];
#pragma unroll
        for (int r = 0; r < 4; ++r) {
          float v = __expf(acc[qm][i_][j_][r] * 0.03125f);
          if (maskT && (s0 + r) > (t + moff)) v = 0.f;
          e[r] = v;
          sj[j_] += v;
        }
        o.x = f32_to_bf16(e[0]);
        o.y = f32_to_bf16(e[1]);
        o.z = f32_to_bf16(e[2]);
        o.w = f32_to_bf16(e[3]);
        *(ushort4*)(lds + t * 264 + s0) = o;
      }
    }
#pragma unroll
  for (int j_ = 0; j_ < 2; ++j_) {
    float v = sj[j_];
    v += __shfl_xor(v, 16);
    v += __shfl_xor(v, 32);
    if (quad == 0)
      atomicAdd(&sums[(size_t)b * 2048 + rt * 128 + wc * 32 + j_ * 16 + l15], v);
  }
  __syncthreads();
  const int ld = (rt + 1) * 128;
  const int nc = ld - ct * 256;  // 256 normally; 128 on even-rt last tile
  u16* Out = Spk + (size_t)b * S_BATCH + (size_t)(rt * (rt + 1) / 2) * 16384 +
             ct * 256;
  if (nc >= 256) {
#pragma unroll
    for (int p = 0; p < 8; ++p) {
      const int row = p * 16 + (tid >> 5);
      const int c0 = (tid & 31) * 8;
      const uint4 v = *(const uint4*)(lds + row * 264 + c0);
      *(uint4*)(Out + (size_t)row * ld + c0) = v;
    }
  } else {
#pragma unroll
    for (int p = 0; p < 4; ++p) {
      const int row = p * 32 + (tid >> 4);
      const int c0 = (tid & 15) * 8;
      const uint4 v = *(const uint4*)(lds + row * 264 + c0);
      *(uint4*)(Out + (size_t)row * ld + c0) = v;
    }
  }
#undef ST_A0
#undef ST_A1
#undef ST_B
#undef SLOADA
#undef SLOADB
#undef SMMA
#undef BAR
#undef WLG0
#undef PRIO1
#undef PRIO0
#undef WVM4
#undef WVM0
}

// ---------------------------------------------------------------------------
// PV — 256(c) x 128(t) tile, 8 waves, 2 phases/K-tile, phase-head loads.
// out[b][t][c] = (1/sums[b][t]) * sum_s S[b][t][s] * Vt[b][c][s].
// A = Vt rows (c, lda=2048): reg-quad packs c -> float4 epilogue writes.
// B = Spk strip rt (128 t-rows, ldb=(rt+1)*128).  K = (rt+1)*2 tiles of 64.
// Fragment: c = qm*128 + wr*64 + i*16 + quad*4 + r ; t = wc*32 + j*16 + l15.
// Grid 512 = 2 halves x 8 rt x 4 ct x 8 b; boustrophedon rt order balances
// the two 1-block/CU rounds (CU gets ~17 of 136 work units either way).
// ---------------------------------------------------------------------------
__global__ __launch_bounds__(512, 2) void pv_kernel(const u16* __restrict__ Spk,
                                                    const u16* __restrict__ Vt,
                                                    const float* __restrict__ sums,
                                                    float* __restrict__ Out) {
  __shared__ __align__(16) u16 lds[49152];  // 96 KB

  const int id = blockIdx.x;       // 0..511
  const int hf = id >> 8;
  const int rr_ = id & 255;
  const int rt = hf ? (rr_ >> 5) : 15 - (rr_ >> 5);
  const int ct = (rr_ >> 3) & 3;
  const int b = rr_ & 7;

  const int ldb = (rt + 1) * 128;
  const int nk2 = rt + 1;          // K-tile pairs; kIters = 2*nk2

  const int tid = threadIdx.x;
  const int srow = tid >> 3;
  const int sgrp = ((tid & 7) - srow) & 7;
  const u16* A = Vt + ((size_t)b * 1024 + ct * 256) * 2048;   // 256 c-rows
  const u16* B = Spk + (size_t)b * S_BATCH +
                 (size_t)(rt * (rt + 1) / 2) * 16384;         // 128 t-rows
  const u16* Ag = A + (size_t)srow * 2048 + sgrp * 8;
  const u16* Bg = B + (size_t)srow * ldb + sgrp * 8;
  char* ldsDst = (char*)lds + tid * 16;

#define ST_A0(kt) do { const u16* s_ = Ag + (kt) * 64;            char* d_ = ldsDst + (((kt) & 1) * 49152);         gl2lds16(s_, d_); gl2lds16(s_ + 131072, d_ + 8192); } while (0)
#define ST_A1(kt) do { const u16* s_ = Ag + 262144 + (kt) * 64;   char* d_ = ldsDst + (((kt) & 1) * 49152) + 16384; gl2lds16(s_, d_); gl2lds16(s_ + 131072, d_ + 8192); } while (0)
#define ST_B(kt)  do { const u16* s_ = Bg + (kt) * 64;            char* d_ = ldsDst + (((kt) & 1) * 49152) + 32768; gl2lds16(s_, d_); gl2lds16(s_ + (size_t)64 * ldb, d_ + 8192); } while (0)

  // Prologue: K-tile 0 complete + A0/B of K-tile 1.
  ST_A0(0); ST_B(0); ST_A1(0);
  ST_A0(1); ST_B(1);

  const int lane = tid & 63, wid = tid >> 6;
  const int wr = wid >> 2, wc = wid & 3;
  const int l15 = lane & 15, quad = lane >> 4;

  int aoff[4][2], boff[2][2];
#pragma unroll
  for (int i_ = 0; i_ < 4; ++i_) {
    const int arow = wr * 64 + i_ * 16 + l15;
#pragma unroll
    for (int k_ = 0; k_ < 2; ++k_)
      aoff[i_][k_] = arow * 64 + ((k_ * 4 + quad + arow) & 7) * 8;
  }
#pragma unroll
  for (int j_ = 0; j_ < 2; ++j_) {
    const int brow = wc * 32 + j_ * 16 + l15;
#pragma unroll
    for (int k_ = 0; k_ < 2; ++k_)
      boff[j_][k_] = brow * 64 + ((k_ * 4 + quad + brow) & 7) * 8;
  }

  f32x4 acc[2][4][2];
#pragma unroll
  for (int q_ = 0; q_ < 2; ++q_)
#pragma unroll
    for (int i_ = 0; i_ < 4; ++i_)
#pragma unroll
      for (int j_ = 0; j_ < 2; ++j_)
        acc[q_][i_][j_] = (f32x4){0.f, 0.f, 0.f, 0.f};

  bf16x8 af[4][2], bfr[2][2];

#define SLOADA(qm, buf) do { const u16* p_ = lds + (buf) * 24576 + (qm) * 8192; \
  _Pragma("unroll") for (int i_ = 0; i_ < 4; ++i_) \
  _Pragma("unroll") for (int k_ = 0; k_ < 2; ++k_) \
    af[i_][k_] = *(const bf16x8*)(p_ + aoff[i_][k_]); } while (0)
#define SLOADB(buf) do { const u16* p_ = lds + (buf) * 24576 + 16384; \
  _Pragma("unroll") for (int j_ = 0; j_ < 2; ++j_) \
  _Pragma("unroll") for (int k_ = 0; k_ < 2; ++k_) \
    bfr[j_][k_] = *(const bf16x8*)(p_ + boff[j_][k_]); } while (0)
#define SMMA(qm) do { \
  _Pragma("unroll") for (int i_ = 0; i_ < 4; ++i_) \
  _Pragma("unroll") for (int j_ = 0; j_ < 2; ++j_) \
  _Pragma("unroll") for (int k_ = 0; k_ < 2; ++k_) \
    acc[qm][i_][j_] = __builtin_amdgcn_mfma_f32_16x16x32_bf16( \
        af[i_][k_], bfr[j_][k_], acc[qm][i_][j_], 0, 0, 0); } while (0)

#define BAR __builtin_amdgcn_s_barrier()
#define WLG0 asm volatile("s_waitcnt lgkmcnt(0)")
#define PRIO1 __builtin_amdgcn_s_setprio(1)
#define PRIO0 __builtin_amdgcn_s_setprio(0)
#define WVM4 asm volatile("s_waitcnt vmcnt(4)" ::: "memory")
#define WVM0 asm volatile("s_waitcnt vmcnt(0)" ::: "memory")

  WVM4;  // K-tile 0 landed
  BAR;

#pragma unroll 1
  for (int it = 0; it < nk2 - 1; ++it) {
    const int j0 = 2 * it;
    SLOADA(0, 0); SLOADB(0); ST_A1(j0 + 1);
    BAR; WLG0; PRIO1; SMMA(0); PRIO0; BAR;
    SLOADA(1, 0); ST_A0(j0 + 2); ST_B(j0 + 2);
    BAR; WLG0; PRIO1; SMMA(1); PRIO0;
    WVM4;  // K-tile j0+1 landed
    BAR;
    SLOADA(0, 1); SLOADB(1); ST_A1(j0 + 2);
    BAR; WLG0; PRIO1; SMMA(0); PRIO0; BAR;
    SLOADA(1, 1); ST_A0(j0 + 3); ST_B(j0 + 3);
    BAR; WLG0; PRIO1; SMMA(1); PRIO0;
    WVM4;  // K-tile j0+2 landed
    BAR;
  }
  {  // tail: K-tiles 2*nk2-2 (buf0), 2*nk2-1 (buf1)
    SLOADA(0, 0); SLOADB(0); ST_A1(2 * nk2 - 1);
    BAR; WLG0; PRIO1; SMMA(0); PRIO0; BAR;
    SLOADA(1, 0);
    BAR; WLG0; PRIO1; SMMA(1); PRIO0;
    WVM0;  // drain (last K-tile complete)
    BAR;
    SLOADA(0, 1); SLOADB(1);
    BAR; WLG0; PRIO1; SMMA(0); PRIO0; BAR;
    SLOADA(1, 1);
    BAR; WLG0; PRIO1; SMMA(1); PRIO0; BAR;
  }

  // Epilogue: scale by 1/sums, stage fp32 [t 128][c 132] per c-half, store.
  float* ftile = (float*)lds;   // 128 x 132 fp32 = 67584 B (fits 96KB)
  const float* sumsb = sums + (size_t)b * 2048 + rt * 128;
  float* Ob = Out + (size_t)b * 2048 * 1024 + (size_t)(rt * 128) * 1024 +
              ct * 256;
  float iv[2];
#pragma unroll
  for (int j_ = 0; j_ < 2; ++j_)
    iv[j_] = 1.0f / sumsb[wc * 32 + j_ * 16 + l15];
#pragma unroll
  for (int qm = 0; qm < 2; ++qm) {
    if (qm) __syncthreads();
#pragma unroll
    for (int i_ = 0; i_ < 4; ++i_) {
      const int c0 = wr * 64 + i_ * 16 + quad * 4;
#pragma unroll
      for (int j_ = 0; j_ < 2; ++j_) {
        const int t = wc * 32 + j_ * 16 + l15;
        float4 v;
        v.x = acc[qm][i_][j_][0] * iv[j_];
        v.y = acc[qm][i_][j_][1] * iv[j_];
        v.z = acc[qm][i_][j_][2] * iv[j_];
        v.w = acc[qm][i_][j_][3] * iv[j_];
        *(float4*)(ftile + t * 132 + c0) = v;
      }
    }
    __syncthreads();
#pragma unroll
    for (int p = 0; p < 8; ++p) {
      const int row = p * 16 + (tid >> 5);
      const int c0f = (tid & 31) * 4;
      const float4 v = *(const float4*)(ftile + row * 132 + c0f);
      *(float4*)(Ob + (size_t)row * 1024 + qm * 128 + c0f) = v;
    }
  }
#undef ST_A0
#undef ST_A1
#undef ST_B
#undef SLOADA
#undef SLOADB
#undef SMMA
#undef BAR
#undef WLG0
#undef PRIO1
#undef PRIO0
#undef WVM4
#undef WVM0
}

// ---------------------------------------------------------------------------
extern "C" void kernel_launch(void* const* d_in, const int* in_sizes, int n_in,
                              void* d_out, int out_size, void* d_ws,
                              size_t ws_size, hipStream_t stream) {
  const float* x = (const float*)d_in[0];
  const float* wq = (const float*)d_in[1];
  const float* bq = (const float*)d_in[2];
  const float* wk = (const float*)d_in[3];
  const float* bk = (const float*)d_in[4];
  const float* wv = (const float*)d_in[5];
  const float* bv = (const float*)d_in[6];
  float* out = (float*)d_out;
  char* ws = (char*)d_ws;

  // Workspace layout (<=160 MB):
  //   [0,32M)      Qb bf16 [16384][1024]
  //   [32,64M)     Kb bf16 [16384][1024]
  //   [64,96M)     Vt bf16 [8][1024][2048]
  //   [96,130.1M)  Spk bf16 packed triangular [8][136*16384]
  //   [132,132.07M) sums fp32 [16384]
  //   [134,140M)   wb bf16 [3][1024][1024]
  //   xb (32MB @96M) aliases Spk: dead after qkv pass.
  u16* Qb = (u16*)(ws);
  u16* Kb = (u16*)(ws + ((size_t)32 << 20));
  u16* Vt = (u16*)(ws + ((size_t)64 << 20));
  u16* Spk = (u16*)(ws + ((size_t)96 << 20));
  u16* xb = (u16*)(ws + ((size_t)96 << 20));   // alias: dies before Spk written
  float* sums = (float*)(ws + ((size_t)132 << 20));
  u16* wb = (u16*)(ws + ((size_t)134 << 20));

  // pass 0: casts + sums zero-init
  cast_f32_to_bf16_kernel<<<16384, 256, 0, stream>>>(x, xb, 16777216 / 4);
  cast_w_kernel<<<dim3(512, 4), 256, 0, stream>>>(wq, wk, wv, wb, sums);

  // pass 1: fused Q,K,V projections (V transposed), 256^2 8-phase
  qkv_kernel<<<768, 512, 0, stream>>>(xb, wb, bq, bk, bv, Qb, Kb, Vt);

  // pass 2: causal exp-scores, 256x128-tile 8-phase (packed layout unchanged)
  score_kernel<<<576, 512, 0, stream>>>(Kb, Qb, Spk, sums);

  // pass 3: P @ V, 256x128-tile 8-phase, scaled by 1/sums
  pv_kernel<<<512, 512, 0, stream>>>(Spk, Vt, sums, out);
}

// Round 4
// 329.796 us; speedup vs baseline: 1.0406x; 1.0061x over previous
//
#include <hip/hip_runtime.h>
#include <stdint.h>

typedef unsigned short u16;
typedef __attribute__((ext_vector_type(8))) __bf16 bf16x8;
typedef __attribute__((ext_vector_type(4))) float f32x4;

#define DEVI __device__ __forceinline__

DEVI u16 f32_to_bf16(float f) {
  uint32_t u = __builtin_bit_cast(uint32_t, f);
  u += 0x7FFFu + ((u >> 16) & 1u);   // RNE; inputs are never NaN here
  return (u16)(u >> 16);
}

DEVI void gl2lds16(const void* g, void* l) {
  __builtin_amdgcn_global_load_lds(
      (const __attribute__((address_space(1))) void*)g,
      (__attribute__((address_space(3))) void*)l, 16, 0, 0);
}

// S is packed triangular: per batch, strip rt (128 rows) has row stride
// (rt+1)*128 and begins at tri(rt)*16384 u16.  Per-batch size 136*16384 u16.
#define S_BATCH 2228224  // u16 elements per batch = 136*16384

// ---------------------------------------------------------------------------
__global__ void cast_f32_to_bf16_kernel(const float* __restrict__ src,
                                        u16* __restrict__ dst, int n4) {
  int i = blockIdx.x * blockDim.x + threadIdx.x;
  const int stride = gridDim.x * blockDim.x;
  for (; i < n4; i += stride) {
    const float4 v = ((const float4*)src)[i];
    ushort4 o;
    o.x = f32_to_bf16(v.x);
    o.y = f32_to_bf16(v.y);
    o.z = f32_to_bf16(v.z);
    o.w = f32_to_bf16(v.w);
    ((ushort4*)dst)[i] = o;
  }
}

// weights -> contiguous bf16 [3][1024][1024]; z==3 zero-inits sums[16384].
__global__ void cast_w_kernel(const float* __restrict__ wq,
                              const float* __restrict__ wk,
                              const float* __restrict__ wv,
                              u16* __restrict__ wb, float* __restrict__ sums) {
  const int z = blockIdx.y;
  if (z == 3) {
    int i = blockIdx.x * blockDim.x + threadIdx.x;
    if (i < 4096) ((float4*)sums)[i] = (float4){0.f, 0.f, 0.f, 0.f};
    return;
  }
  const float* src = (z == 0) ? wq : (z == 1) ? wk : wv;
  u16* dst = wb + (size_t)z * 1048576;
  int i = blockIdx.x * blockDim.x + threadIdx.x;
  const int stride = gridDim.x * blockDim.x;
  for (; i < 262144; i += stride) {
    const float4 v = ((const float4*)src)[i];
    ushort4 o;
    o.x = f32_to_bf16(v.x);
    o.y = f32_to_bf16(v.y);
    o.z = f32_to_bf16(v.z);
    o.w = f32_to_bf16(v.w);
    ((ushort4*)dst)[i] = o;
  }
}

// ---------------------------------------------------------------------------
// Fused Q/K/V projection — PERSISTENT 256x256-tile, 8-wave, 8-phase.
// Grid 256 = 1 block/CU, ONE round; each block runs z=0(Q),1(K),2(V) for its
// (tmt,tct).  z->z+1 transition overlaps: next K-tile0 staging (buf0) ||
// current epilogue (staged in buf1, stride-256 + row*8 col rotation) || store
// drain, with raw barriers + lgkmcnt-only waits (no vmcnt(0) until needed).
// vmcnt(22) at transition end is robust for any bias-load CSE (stores=16,
// K1=6 are always the 22 newest; K0 retired).  First P4's vmcnt(6) then
// force-drains the stores after ~5 phases of overlap.
// Fragment (qm,qn,i,j): m = qm*128+wr*64+i*16+quad*4+r ; n = qn*128+wc*32+
// j*16+l15.  LDS 128KB: 2 bufs x {A0,A1,B0,B1} 16KB, row stride 64 u16,
// per-row rotated column groups (conflict-free, gl_lds-linear).
// ---------------------------------------------------------------------------
__global__ __launch_bounds__(512, 2) void qkv_kernel(
    const u16* __restrict__ xb, const u16* __restrict__ wb,
    const float* __restrict__ bq, const float* __restrict__ bk,
    const float* __restrict__ bv, u16* __restrict__ Qb, u16* __restrict__ Kb,
    u16* __restrict__ Vt) {
  __shared__ __align__(16) u16 lds[65536];  // 128 KB

  const int id = blockIdx.x;        // 0..255
  const int xcd = id & 7;           // block->XCD round-robin
  const int local = id >> 3;        // 0..31
  const int tct = local & 3;        // c-tile 0..3
  const int tmt = xcd * 8 + (local >> 2);  // t-tile 0..63 (8 x-panels/XCD)

  const int tid = threadIdx.x;
  const int srow = tid >> 3;                 // staged row 0..63 (+64 2nd load)
  const int sgrp = ((tid & 7) - srow) & 7;   // rotated source column-group
  char* ldsDst = (char*)lds + tid * 16;

  const size_t rowoff = (size_t)srow * 1024 + sgrp * 8;
  const u16* xpan = xb + (size_t)(tmt * 256) * 1024 + rowoff;
  const u16* wpanQ = wb + (size_t)(tct * 256) * 1024 + rowoff;
  const u16* wpanK = wpanQ + 1048576;
  const u16* wpanV = wpanQ + 2097152;

#define STN_A0(ag, kt) do { const u16* s_ = (ag) + (kt) * 64;           char* d_ = ldsDst + (((kt) & 1) * 65536);         gl2lds16(s_, d_); gl2lds16(s_ + 65536, d_ + 8192); } while (0)
#define STN_A1(ag, kt) do { const u16* s_ = (ag) + 131072 + (kt) * 64;  char* d_ = ldsDst + (((kt) & 1) * 65536) + 16384; gl2lds16(s_, d_); gl2lds16(s_ + 65536, d_ + 8192); } while (0)
#define STN_B0(bg, kt) do { const u16* s_ = (bg) + (kt) * 64;           char* d_ = ldsDst + (((kt) & 1) * 65536) + 32768; gl2lds16(s_, d_); gl2lds16(s_ + 65536, d_ + 8192); } while (0)
#define STN_B1(bg, kt) do { const u16* s_ = (bg) + 131072 + (kt) * 64;  char* d_ = ldsDst + (((kt) & 1) * 65536) + 49152; gl2lds16(s_, d_); gl2lds16(s_ + 65536, d_ + 8192); } while (0)
#define ST_A0(kt) STN_A0(agCur, kt)
#define ST_A1(kt) STN_A1(agCur, kt)
#define ST_B0(kt) STN_B0(bgCur, kt)
#define ST_B1(kt) STN_B1(bgCur, kt)

  const int lane = tid & 63, wid = tid >> 6;
  const int wr = wid >> 2, wc = wid & 3;
  const int l15 = lane & 15, quad = lane >> 4;

  int aoff[4][2], boff[2][2];
#pragma unroll
  for (int i_ = 0; i_ < 4; ++i_) {
    const int arow = wr * 64 + i_ * 16 + l15;
#pragma unroll
    for (int k_ = 0; k_ < 2; ++k_)
      aoff[i_][k_] = arow * 64 + ((k_ * 4 + quad + arow) & 7) * 8;
  }
#pragma unroll
  for (int j_ = 0; j_ < 2; ++j_) {
    const int brow = wc * 32 + j_ * 16 + l15;
#pragma unroll
    for (int k_ = 0; k_ < 2; ++k_)
      boff[j_][k_] = brow * 64 + ((k_ * 4 + quad + brow) & 7) * 8;
  }

  f32x4 acc[2][2][4][2];
  bf16x8 af[4][2], bfr[2][2][2];

#define LOADA(qm, buf) do { const u16* p_ = lds + (buf) * 32768 + (qm) * 8192; \
  _Pragma("unroll") for (int i_ = 0; i_ < 4; ++i_) \
  _Pragma("unroll") for (int k_ = 0; k_ < 2; ++k_) \
    af[i_][k_] = *(const bf16x8*)(p_ + aoff[i_][k_]); } while (0)
#define LOADB(qn, buf) do { const u16* p_ = lds + (buf) * 32768 + 16384 + (qn) * 8192; \
  _Pragma("unroll") for (int j_ = 0; j_ < 2; ++j_) \
  _Pragma("unroll") for (int k_ = 0; k_ < 2; ++k_) \
    bfr[qn][j_][k_] = *(const bf16x8*)(p_ + boff[j_][k_]); } while (0)
#define MMA(qm, qn) do { \
  _Pragma("unroll") for (int i_ = 0; i_ < 4; ++i_) \
  _Pragma("unroll") for (int j_ = 0; j_ < 2; ++j_) \
  _Pragma("unroll") for (int k_ = 0; k_ < 2; ++k_) \
    acc[qm][qn][i_][j_] = __builtin_amdgcn_mfma_f32_16x16x32_bf16( \
        af[i_][k_], bfr[qn][j_][k_], acc[qm][qn][i_][j_], 0, 0, 0); } while (0)

#define BAR __builtin_amdgcn_s_barrier()
#define WLG0 asm volatile("s_waitcnt lgkmcnt(0)")
#define WLG8 asm volatile("s_waitcnt lgkmcnt(8)")
#define PRIO1 __builtin_amdgcn_s_setprio(1)
#define PRIO0 __builtin_amdgcn_s_setprio(0)
#define WVM6 asm volatile("s_waitcnt vmcnt(6)" ::: "memory")
#define WVM22 asm volatile("s_waitcnt vmcnt(22)" ::: "memory")
#define WVM0 asm volatile("s_waitcnt vmcnt(0)" ::: "memory")
#define FENCE asm volatile("" ::: "memory")

  const u16* agCur = wpanQ;
  const u16* bgCur = xpan;
  int m0 = tct * 256, n0 = tmt * 256;

  // Prologue (z=0): K-tile 0 complete + A0/B0/B1 of K-tile 1 (7 half-tiles).
  ST_A0(0); ST_B0(0); ST_B1(0); ST_A1(0);
  ST_A0(1); ST_B0(1); ST_B1(1);
  WVM6;  // K-tile 0 landed
  BAR;

#pragma unroll 1
  for (int z = 0; z < 3; ++z) {
#pragma unroll
    for (int a_ = 0; a_ < 2; ++a_)
#pragma unroll
      for (int b_ = 0; b_ < 2; ++b_)
#pragma unroll
        for (int i_ = 0; i_ < 4; ++i_)
#pragma unroll
          for (int j_ = 0; j_ < 2; ++j_)
            acc[a_][b_][i_][j_] = (f32x4){0.f, 0.f, 0.f, 0.f};

#pragma unroll 1
    for (int it = 0; it < 7; ++it) {
      const int j0 = 2 * it;
      // P1 (0,0) buf0
      LOADA(0, 0); LOADB(0, 0); ST_A1(j0 + 1); WLG8;
      BAR; WLG0; PRIO1; MMA(0, 0); PRIO0; BAR;
      // P2 (0,1)
      LOADB(1, 0); ST_A0(j0 + 2);
      BAR; WLG0; PRIO1; MMA(0, 1); PRIO0; BAR;
      // P3 (1,1)
      LOADA(1, 0); ST_B0(j0 + 2);
      BAR; WLG0; PRIO1; MMA(1, 1); PRIO0; BAR;
      // P4 (1,0)
      ST_B1(j0 + 2);
      BAR; PRIO1; MMA(1, 0); PRIO0;
      WVM6;  // K-tile j0+1 landed
      BAR;
      // P5 (0,0) buf1
      LOADA(0, 1); LOADB(0, 1); ST_A1(j0 + 2); WLG8;
      BAR; WLG0; PRIO1; MMA(0, 0); PRIO0; BAR;
      // P6 (0,1)
      LOADB(1, 1); ST_A0(j0 + 3);
      BAR; WLG0; PRIO1; MMA(0, 1); PRIO0; BAR;
      // P7 (1,1)
      LOADA(1, 1); ST_B0(j0 + 3);
      BAR; WLG0; PRIO1; MMA(1, 1); PRIO0; BAR;
      // P8 (1,0)
      ST_B1(j0 + 3);
      BAR; PRIO1; MMA(1, 0); PRIO0;
      WVM6;  // K-tile j0+2 landed
      BAR;
    }
    {  // it = 7: K-tiles 14 (buf0) / 15 (buf1); only A1(15) left to stage
      LOADA(0, 0); LOADB(0, 0); ST_A1(15); WLG8;
      BAR; WLG0; PRIO1; MMA(0, 0); PRIO0; BAR;
      LOADB(1, 0);
      BAR; WLG0; PRIO1; MMA(0, 1); PRIO0; BAR;
      LOADA(1, 0);
      BAR; WLG0; PRIO1; MMA(1, 1); PRIO0; BAR;
      BAR; PRIO1; MMA(1, 0); PRIO0;
      WVM0;  // drain: K-tile 15 landed
      BAR;
      LOADA(0, 1); LOADB(0, 1); WLG8;
      BAR; WLG0; PRIO1; MMA(0, 0); PRIO0; BAR;
      LOADB(1, 1);
      BAR; WLG0; PRIO1; MMA(0, 1); PRIO0; BAR;
      LOADA(1, 1);
      BAR; WLG0; PRIO1; MMA(1, 1); PRIO0; BAR;
      PRIO1; MMA(1, 0); PRIO0;
      BAR;  // mainloop done; all LDS reads drained, 0 gl_lds outstanding
    }

    if (z < 3 - 1) {
      // ---- transition: next-z prologue overlapped with Q/K epilogue ----
      const u16* agN = (z == 0) ? wpanK : xpan;
      const u16* bgN = (z == 0) ? xpan : wpanV;
      FENCE;
      // T1: next K-tile 0 -> buf0 (8 gl_lds)
      STN_A0(agN, 0); STN_B0(bgN, 0); STN_B1(bgN, 0); STN_A1(agN, 0);
      FENCE;
      // epilogue of current z (Q or K): stage in buf1 (stride 256, row*8
      // column rotation -> 2-way banks), raw barriers, lgkm-only waits.
      {
        u16* stg = lds + 32768;  // buf1, 32768 u16 = 64 KB
        const float* bias = (z == 0) ? bq : bk;
        u16* Out = (z == 0) ? Qb : Kb;
#pragma unroll
        for (int th = 0; th < 2; ++th) {
          if (th) { WLG0; BAR; }   // th0 reads done chip-wide before overwrite
#pragma unroll
          for (int qm = 0; qm < 2; ++qm)
#pragma unroll
            for (int i_ = 0; i_ < 4; ++i_) {
              const int c = qm * 128 + wr * 64 + i_ * 16 + quad * 4;
              const float4 b4 = *(const float4*)(bias + m0 + c);
#pragma unroll
              for (int j_ = 0; j_ < 2; ++j_) {
                const int row = wc * 32 + j_ * 16 + l15;
                ushort4 o;
                o.x = f32_to_bf16(acc[qm][th][i_][j_][0] + b4.x);
                o.y = f32_to_bf16(acc[qm][th][i_][j_][1] + b4.y);
                o.z = f32_to_bf16(acc[qm][th][i_][j_][2] + b4.z);
                o.w = f32_to_bf16(acc[qm][th][i_][j_][3] + b4.w);
                *(ushort4*)(stg + row * 256 + ((c + row * 8) & 255)) = o;
              }
            }
          WLG0; BAR;               // staging visible to all waves
#pragma unroll
          for (int p = 0; p < 8; ++p) {
            const int row = p * 16 + (tid >> 5);
            const int c0 = (tid & 31) * 8;
            const uint4 v =
                *(const uint4*)(stg + row * 256 + ((c0 + row * 8) & 255));
            *(uint4*)(Out + (size_t)(n0 + th * 128 + row) * 1024 + m0 + c0) = v;
          }
        }
        WLG0; BAR;                 // th1 reads drained; stg reusable
      }
      FENCE;
      // T3: next K-tile 1 partial (A0/B0/B1 -> buf1; A1(1) staged at P1)
      STN_A0(agN, 1); STN_B0(bgN, 1); STN_B1(bgN, 1);
      // T4: robust entry wait — stores(16)+K1(6) are the 22 newest; K-tile 0
      // (oldest) retired for any bias-load CSE/hoist outcome.
      WVM22;
      BAR;
      agCur = agN;
      bgCur = bgN;
      m0 = (z == 0) ? tct * 256 : tmt * 256;
      n0 = (z == 0) ? tmt * 256 : tct * 256;
    }
  }

  // Final epilogue (z=2, V): [c][t] staging, transposed store to Vt.
  {
    const int b = m0 >> 11;
    const int t0b = m0 & 2047;
    u16* Out = Vt + (size_t)b * 2097152;
#pragma unroll
    for (int th = 0; th < 2; ++th) {
      if (th) __syncthreads();
#pragma unroll
      for (int j_ = 0; j_ < 2; ++j_) {
        const int row = wc * 32 + j_ * 16 + l15;      // c within half
        const float bb = bv[n0 + th * 128 + row];
#pragma unroll
        for (int qm = 0; qm < 2; ++qm)
#pragma unroll
          for (int i_ = 0; i_ < 4; ++i_) {
            const int c = qm * 128 + wr * 64 + i_ * 16 + quad * 4;  // t
            ushort4 o;
            o.x = f32_to_bf16(acc[qm][th][i_][j_][0] + bb);
            o.y = f32_to_bf16(acc[qm][th][i_][j_][1] + bb);
            o.z = f32_to_bf16(acc[qm][th][i_][j_][2] + bb);
            o.w = f32_to_bf16(acc[qm][th][i_][j_][3] + bb);
            *(ushort4*)(lds + row * 264 + c) = o;     // [c][t]
          }
      }
      __syncthreads();
#pragma unroll
      for (int p = 0; p < 8; ++p) {
        const int row = p * 16 + (tid >> 5);
        const int c0 = (tid & 31) * 8;
        const uint4 v = *(const uint4*)(lds + row * 264 + c0);
        *(uint4*)(Out + (size_t)(n0 + th * 128 + row) * 2048 + t0b + c0) = v;
      }
    }
  }
#undef STN_A0
#undef STN_A1
#undef STN_B0
#undef STN_B1
#undef ST_A0
#undef ST_A1
#undef ST_B0
#undef ST_B1
#undef LOADA
#undef LOADB
#undef MMA
#undef BAR
#undef WLG0
#undef WLG8
#undef PRIO1
#undef PRIO0
#undef WVM6
#undef WVM22
#undef WVM0
#undef FENCE
}

// ---------------------------------------------------------------------------
// Scores — 256(s) x 128(t) tile, 8 waves, 2 phases/K-tile, phase-head loads.
// S[b][t][s] = exp((K.Q)/32), causal-masked, packed triangular.
// Fragment: s = qm*128 + wr*64 + i*16 + quad*4 + r ; t = wc*32 + j*16 + l15.
// LDS 96KB: 2 bufs x {A0,A1,B} x 16KB (row stride 64 u16, rotated groups).
// Grid 576 = 8 batches (one per XCD) x 72 tiles; all tiles equal cost.
// ---------------------------------------------------------------------------
__global__ __launch_bounds__(512, 2) void score_kernel(const u16* __restrict__ Kb,
                                                       const u16* __restrict__ Qb,
                                                       u16* __restrict__ Spk,
                                                       float* __restrict__ sums) {
  __shared__ __align__(16) u16 lds[49152];  // 96 KB

  const int id = blockIdx.x;   // 0..575
  const int b = id & 7;        // batch per XCD: K/Q tiles stay in XCD L2
  const int l = id >> 3;       // 0..71
  int k = (int)((sqrtf(4.f * l + 1.f) - 1.f) * 0.5f);
  if (k * (k + 1) > l) --k;
  if ((k + 1) * (k + 2) <= l) ++k;
  const int off = l - k * (k + 1);
  const int hi = (off >= (k + 1));
  const int rt = 2 * k + hi;           // t-strip 0..15 (128 rows)
  const int ct = off - (hi ? (k + 1) : 0);  // s-tile 0..k (256 cols)
  const bool maskT = (ct == k);        // only the last s-tile crosses diag

  const int tid = threadIdx.x;
  const int srow = tid >> 3;
  const int sgrp = ((tid & 7) - srow) & 7;
  const u16* A = Qb + ((size_t)b * 2048 + ct * 256) * 1024;  // 256 s-rows
  const u16* B = Kb + ((size_t)b * 2048 + rt * 128) * 1024;  // 128 t-rows
  const u16* Ag = A + (size_t)srow * 1024 + sgrp * 8;
  const u16* Bg = B + (size_t)srow * 1024 + sgrp * 8;
  char* ldsDst = (char*)lds + tid * 16;

#define ST_A0(kt) do { const u16* s_ = Ag + (kt) * 64;           char* d_ = ldsDst + (((kt) & 1) * 49152);         gl2lds16(s_, d_); gl2lds16(s_ + 65536, d_ + 8192); } while (0)
#define ST_A1(kt) do { const u16* s_ = Ag + 131072 + (kt) * 64;  char* d_ = ldsDst + (((kt) & 1) * 49152) + 16384; gl2lds16(s_, d_); gl2lds16(s_ + 65536, d_ + 8192); } while (0)
#define ST_B(kt)  do { const u16* s_ = Bg + (kt) * 64;           char* d_ = ldsDst + (((kt) & 1) * 49152) + 32768; gl2lds16(s_, d_); gl2lds16(s_ + 65536, d_ + 8192); } while (0)

  // Prologue: K-tile 0 complete + A0/B of K-tile 1 (A1(1) staged at Q1).
  ST_A0(0); ST_B(0); ST_A1(0);
  ST_A0(1); ST_B(1);

  const int lane = tid & 63, wid = tid >> 6;
  const int wr = wid >> 2, wc = wid & 3;
  const int l15 = lane & 15, quad = lane >> 4;

  int aoff[4][2], boff[2][2];
#pragma unroll
  for (int i_ = 0; i_ < 4; ++i_) {
    const int arow = wr * 64 + i_ * 16 + l15;
#pragma unroll
    for (int k_ = 0; k_ < 2; ++k_)
      aoff[i_][k_] = arow * 64 + ((k_ * 4 + quad + arow) & 7) * 8;
  }
#pragma unroll
  for (int j_ = 0; j_ < 2; ++j_) {
    const int brow = wc * 32 + j_ * 16 + l15;
#pragma unroll
    for (int k_ = 0; k_ < 2; ++k_)
      boff[j_][k_] = brow * 64 + ((k_ * 4 + quad + brow) & 7) * 8;
  }

  f32x4 acc[2][4][2];
#pragma unroll
  for (int q_ = 0; q_ < 2; ++q_)
#pragma unroll
    for (int i_ = 0; i_ < 4; ++i_)
#pragma unroll
      for (int j_ = 0; j_ < 2; ++j_)
        acc[q_][i_][j_] = (f32x4){0.f, 0.f, 0.f, 0.f};

  bf16x8 af[4][2], bfr[2][2];

#define SLOADA(qm, buf) do { const u16* p_ = lds + (buf) * 24576 + (qm) * 8192; \
  _Pragma("unroll") for (int i_ = 0; i_ < 4; ++i_) \
  _Pragma("unroll") for (int k_ = 0; k_ < 2; ++k_) \
    af[i_][k_] = *(const bf16x8*)(p_ + aoff[i_][k_]); } while (0)
#define SLOADB(buf) do { const u16* p_ = lds + (buf) * 24576 + 16384; \
  _Pragma("unroll") for (int j_ = 0; j_ < 2; ++j_) \
  _Pragma("unroll") for (int k_ = 0; k_ < 2; ++k_) \
    bfr[j_][k_] = *(const bf16x8*)(p_ + boff[j_][k_]); } while (0)
#define SMMA(qm) do { \
  _Pragma("unroll") for (int i_ = 0; i_ < 4; ++i_) \
  _Pragma("unroll") for (int j_ = 0; j_ < 2; ++j_) \
  _Pragma("unroll") for (int k_ = 0; k_ < 2; ++k_) \
    acc[qm][i_][j_] = __builtin_amdgcn_mfma_f32_16x16x32_bf16( \
        af[i_][k_], bfr[j_][k_], acc[qm][i_][j_], 0, 0, 0); } while (0)

#define BAR __builtin_amdgcn_s_barrier()
#define WLG0 asm volatile("s_waitcnt lgkmcnt(0)")
#define PRIO1 __builtin_amdgcn_s_setprio(1)
#define PRIO0 __builtin_amdgcn_s_setprio(0)
#define WVM4 asm volatile("s_waitcnt vmcnt(4)" ::: "memory")
#define WVM0 asm volatile("s_waitcnt vmcnt(0)" ::: "memory")

  WVM4;  // K-tile 0 (3 STs) landed
  BAR;

#pragma unroll 1
  for (int it = 0; it < 7; ++it) {
    const int j0 = 2 * it;
    // Q1 (K-tile j0, qm=0)
    SLOADA(0, 0); SLOADB(0); ST_A1(j0 + 1);
    BAR; WLG0; PRIO1; SMMA(0); PRIO0; BAR;
    // Q2 (j0, qm=1)
    SLOADA(1, 0); ST_A0(j0 + 2); ST_B(j0 + 2);
    BAR; WLG0; PRIO1; SMMA(1); PRIO0;
    WVM4;  // K-tile j0+1 landed
    BAR;
    // Q3 (j0+1, qm=0)
    SLOADA(0, 1); SLOADB(1); ST_A1(j0 + 2);
    BAR; WLG0; PRIO1; SMMA(0); PRIO0; BAR;
    // Q4 (j0+1, qm=1)
    SLOADA(1, 1); ST_A0(j0 + 3); ST_B(j0 + 3);
    BAR; WLG0; PRIO1; SMMA(1); PRIO0;
    WVM4;  // K-tile j0+2 landed
    BAR;
  }
  {  // tail: K-tiles 14, 15
    SLOADA(0, 0); SLOADB(0); ST_A1(15);
    BAR; WLG0; PRIO1; SMMA(0); PRIO0; BAR;
    SLOADA(1, 0);
    BAR; WLG0; PRIO1; SMMA(1); PRIO0;
    WVM0;  // drain (K-tile 15 complete)
    BAR;
    SLOADA(0, 1); SLOADB(1);
    BAR; WLG0; PRIO1; SMMA(0); PRIO0; BAR;
    SLOADA(1, 1);
    BAR; WLG0; PRIO1; SMMA(1); PRIO0; BAR;
  }

  // Epilogue: exp/mask, row sums (over s) -> atomicAdd, stage [t][s] 128x256
  // (stride 264) in LDS, store to the packed triangular strip.
  const int moff = (rt & 1) * 128;  // diag shift: mask if s_loc > t_loc + moff
  float sj[2] = {0.f, 0.f};
#pragma unroll
  for (int qm = 0; qm < 2; ++qm)
#pragma unroll
    for (int i_ = 0; i_ < 4; ++i_) {
      const int s0 = qm * 128 + wr * 64 + i_ * 16 + quad * 4;
#pragma unroll
      for (int j_ = 0; j_ < 2; ++j_) {
        const int t = wc * 32 + j_ * 16 + l15;
        ushort4 o;
        float e[4];
#pragma unroll
        for (int r = 0; r < 4; ++r) {
          float v = __expf(acc[qm][i_][j_][r] * 0.03125f);
          if (maskT && (s0 + r) > (t + moff)) v = 0.f;
          e[r] = v;
          sj[j_] += v;
        }
        o.x = f32_to_bf16(e[0]);
        o.y = f32_to_bf16(e[1]);
        o.z = f32_to_bf16(e[2]);
        o.w = f32_to_bf16(e[3]);
        *(ushort4*)(lds + t * 264 + s0) = o;
      }
    }
#pragma unroll
  for (int j_ = 0; j_ < 2; ++j_) {
    float v = sj[j_];
    v += __shfl_xor(v, 16);
    v += __shfl_xor(v, 32);
    if (quad == 0)
      atomicAdd(&sums[(size_t)b * 2048 + rt * 128 + wc * 32 + j_ * 16 + l15], v);
  }
  __syncthreads();
  const int ld = (rt + 1) * 128;
  const int nc = ld - ct * 256;  // 256 normally; 128 on even-rt last tile
  u16* Out = Spk + (size_t)b * S_BATCH + (size_t)(rt * (rt + 1) / 2) * 16384 +
             ct * 256;
  if (nc >= 256) {
#pragma unroll
    for (int p = 0; p < 8; ++p) {
      const int row = p * 16 + (tid >> 5);
      const int c0 = (tid & 31) * 8;
      const uint4 v = *(const uint4*)(lds + row * 264 + c0);
      *(uint4*)(Out + (size_t)row * ld + c0) = v;
    }
  } else {
#pragma unroll
    for (int p = 0; p < 4; ++p) {
      const int row = p * 32 + (tid >> 4);
      const int c0 = (tid & 15) * 8;
      const uint4 v = *(const uint4*)(lds + row * 264 + c0);
      *(uint4*)(Out + (size_t)row * ld + c0) = v;
    }
  }
#undef ST_A0
#undef ST_A1
#undef ST_B
#undef SLOADA
#undef SLOADB
#undef SMMA
#undef BAR
#undef WLG0
#undef PRIO1
#undef PRIO0
#undef WVM4
#undef WVM0
}

// ---------------------------------------------------------------------------
// PV — 256(c) x 128(t) tile, 8 waves, 2 phases/K-tile, phase-head loads.
// out[b][t][c] = (1/sums[b][t]) * sum_s S[b][t][s] * Vt[b][c][s].
// A = Vt rows (c, lda=2048): reg-quad packs c -> float4 epilogue writes.
// B = Spk strip rt (128 t-rows, ldb=(rt+1)*128).  K = (rt+1)*2 tiles of 64.
// Grid 512, 1 block/CU, 2 rounds.  Pairing (verified queue model): first 256
// blocks rt 15..8 (heavy), second 256 rt 7..0 DESCENDING so the earliest-
// freed CUs (lightest round-1 blocks) take the heaviest queued blocks ->
// every CU totals ~17 K-tile-pairs.
// ---------------------------------------------------------------------------
__global__ __launch_bounds__(512, 2) void pv_kernel(const u16* __restrict__ Spk,
                                                    const u16* __restrict__ Vt,
                                                    const float* __restrict__ sums,
                                                    float* __restrict__ Out) {
  __shared__ __align__(16) u16 lds[49152];  // 96 KB

  const int id = blockIdx.x;       // 0..511
  const int hf = id >> 8;
  const int rr_ = id & 255;
  const int rt = (hf ? 7 : 15) - (rr_ >> 5);   // balanced pairing (17/CU)
  const int ct = (rr_ >> 3) & 3;
  const int b = rr_ & 7;

  const int ldb = (rt + 1) * 128;
  const int nk2 = rt + 1;          // K-tile pairs; kIters = 2*nk2

  const int tid = threadIdx.x;
  const int srow = tid >> 3;
  const int sgrp = ((tid & 7) - srow) & 7;
  const u16* A = Vt + ((size_t)b * 1024 + ct * 256) * 2048;   // 256 c-rows
  const u16* B = Spk + (size_t)b * S_BATCH +
                 (size_t)(rt * (rt + 1) / 2) * 16384;         // 128 t-rows
  const u16* Ag = A + (size_t)srow * 2048 + sgrp * 8;
  const u16* Bg = B + (size_t)srow * ldb + sgrp * 8;
  char* ldsDst = (char*)lds + tid * 16;

#define ST_A0(kt) do { const u16* s_ = Ag + (kt) * 64;            char* d_ = ldsDst + (((kt) & 1) * 49152);         gl2lds16(s_, d_); gl2lds16(s_ + 131072, d_ + 8192); } while (0)
#define ST_A1(kt) do { const u16* s_ = Ag + 262144 + (kt) * 64;   char* d_ = ldsDst + (((kt) & 1) * 49152) + 16384; gl2lds16(s_, d_); gl2lds16(s_ + 131072, d_ + 8192); } while (0)
#define ST_B(kt)  do { const u16* s_ = Bg + (kt) * 64;            char* d_ = ldsDst + (((kt) & 1) * 49152) + 32768; gl2lds16(s_, d_); gl2lds16(s_ + (size_t)64 * ldb, d_ + 8192); } while (0)

  // Prologue: K-tile 0 complete + A0/B of K-tile 1.
  ST_A0(0); ST_B(0); ST_A1(0);
  ST_A0(1); ST_B(1);

  const int lane = tid & 63, wid = tid >> 6;
  const int wr = wid >> 2, wc = wid & 3;
  const int l15 = lane & 15, quad = lane >> 4;

  int aoff[4][2], boff[2][2];
#pragma unroll
  for (int i_ = 0; i_ < 4; ++i_) {
    const int arow = wr * 64 + i_ * 16 + l15;
#pragma unroll
    for (int k_ = 0; k_ < 2; ++k_)
      aoff[i_][k_] = arow * 64 + ((k_ * 4 + quad + arow) & 7) * 8;
  }
#pragma unroll
  for (int j_ = 0; j_ < 2; ++j_) {
    const int brow = wc * 32 + j_ * 16 + l15;
#pragma unroll
    for (int k_ = 0; k_ < 2; ++k_)
      boff[j_][k_] = brow * 64 + ((k_ * 4 + quad + brow) & 7) * 8;
  }

  f32x4 acc[2][4][2];
#pragma unroll
  for (int q_ = 0; q_ < 2; ++q_)
#pragma unroll
    for (int i_ = 0; i_ < 4; ++i_)
#pragma unroll
      for (int j_ = 0; j_ < 2; ++j_)
        acc[q_][i_][j_] = (f32x4){0.f, 0.f, 0.f, 0.f};

  bf16x8 af[4][2], bfr[2][2];

#define SLOADA(qm, buf) do { const u16* p_ = lds + (buf) * 24576 + (qm) * 8192; \
  _Pragma("unroll") for (int i_ = 0; i_ < 4; ++i_) \
  _Pragma("unroll") for (int k_ = 0; k_ < 2; ++k_) \
    af[i_][k_] = *(const bf16x8*)(p_ + aoff[i_][k_]); } while (0)
#define SLOADB(buf) do { const u16* p_ = lds + (buf) * 24576 + 16384; \
  _Pragma("unroll") for (int j_ = 0; j_ < 2; ++j_) \
  _Pragma("unroll") for (int k_ = 0; k_ < 2; ++k_) \
    bfr[j_][k_] = *(const bf16x8*)(p_ + boff[j_][k_]); } while (0)
#define SMMA(qm) do { \
  _Pragma("unroll") for (int i_ = 0; i_ < 4; ++i_) \
  _Pragma("unroll") for (int j_ = 0; j_ < 2; ++j_) \
  _Pragma("unroll") for (int k_ = 0; k_ < 2; ++k_) \
    acc[qm][i_][j_] = __builtin_amdgcn_mfma_f32_16x16x32_bf16( \
        af[i_][k_], bfr[j_][k_], acc[qm][i_][j_], 0, 0, 0); } while (0)

#define BAR __builtin_amdgcn_s_barrier()
#define WLG0 asm volatile("s_waitcnt lgkmcnt(0)")
#define PRIO1 __builtin_amdgcn_s_setprio(1)
#define PRIO0 __builtin_amdgcn_s_setprio(0)
#define WVM4 asm volatile("s_waitcnt vmcnt(4)" ::: "memory")
#define WVM0 asm volatile("s_waitcnt vmcnt(0)" ::: "memory")

  WVM4;  // K-tile 0 landed
  BAR;

#pragma unroll 1
  for (int it = 0; it < nk2 - 1; ++it) {
    const int j0 = 2 * it;
    SLOADA(0, 0); SLOADB(0); ST_A1(j0 + 1);
    BAR; WLG0; PRIO1; SMMA(0); PRIO0; BAR;
    SLOADA(1, 0); ST_A0(j0 + 2); ST_B(j0 + 2);
    BAR; WLG0; PRIO1; SMMA(1); PRIO0;
    WVM4;  // K-tile j0+1 landed
    BAR;
    SLOADA(0, 1); SLOADB(1); ST_A1(j0 + 2);
    BAR; WLG0; PRIO1; SMMA(0); PRIO0; BAR;
    SLOADA(1, 1); ST_A0(j0 + 3); ST_B(j0 + 3);
    BAR; WLG0; PRIO1; SMMA(1); PRIO0;
    WVM4;  // K-tile j0+2 landed
    BAR;
  }
  {  // tail: K-tiles 2*nk2-2 (buf0), 2*nk2-1 (buf1)
    SLOADA(0, 0); SLOADB(0); ST_A1(2 * nk2 - 1);
    BAR; WLG0; PRIO1; SMMA(0); PRIO0; BAR;
    SLOADA(1, 0);
    BAR; WLG0; PRIO1; SMMA(1); PRIO0;
    WVM0;  // drain (last K-tile complete)
    BAR;
    SLOADA(0, 1); SLOADB(1);
    BAR; WLG0; PRIO1; SMMA(0); PRIO0; BAR;
    SLOADA(1, 1);
    BAR; WLG0; PRIO1; SMMA(1); PRIO0; BAR;
  }

  // Epilogue: scale by 1/sums, stage fp32 [t 128][c 132] per c-half, store.
  float* ftile = (float*)lds;   // 128 x 132 fp32 = 67584 B (fits 96KB)
  const float* sumsb = sums + (size_t)b * 2048 + rt * 128;
  float* Ob = Out + (size_t)b * 2048 * 1024 + (size_t)(rt * 128) * 1024 +
              ct * 256;
  float iv[2];
#pragma unroll
  for (int j_ = 0; j_ < 2; ++j_)
    iv[j_] = 1.0f / sumsb[wc * 32 + j_ * 16 + l15];
#pragma unroll
  for (int qm = 0; qm < 2; ++qm) {
    if (qm) __syncthreads();
#pragma unroll
    for (int i_ = 0; i_ < 4; ++i_) {
      const int c0 = wr * 64 + i_ * 16 + quad * 4;
#pragma unroll
      for (int j_ = 0; j_ < 2; ++j_) {
        const int t = wc * 32 + j_ * 16 + l15;
        float4 v;
        v.x = acc[qm][i_][j_][0] * iv[j_];
        v.y = acc[qm][i_][j_][1] * iv[j_];
        v.z = acc[qm][i_][j_][2] * iv[j_];
        v.w = acc[qm][i_][j_][3] * iv[j_];
        *(float4*)(ftile + t * 132 + c0) = v;
      }
    }
    __syncthreads();
#pragma unroll
    for (int p = 0; p < 8; ++p) {
      const int row = p * 16 + (tid >> 5);
      const int c0f = (tid & 31) * 4;
      const float4 v = *(const float4*)(ftile + row * 132 + c0f);
      *(float4*)(Ob + (size_t)row * 1024 + qm * 128 + c0f) = v;
    }
  }
#undef ST_A0
#undef ST_A1
#undef ST_B
#undef SLOADA
#undef SLOADB
#undef SMMA
#undef BAR
#undef WLG0
#undef PRIO1
#undef PRIO0
#undef WVM4
#undef WVM0
}

// ---------------------------------------------------------------------------
extern "C" void kernel_launch(void* const* d_in, const int* in_sizes, int n_in,
                              void* d_out, int out_size, void* d_ws,
                              size_t ws_size, hipStream_t stream) {
  const float* x = (const float*)d_in[0];
  const float* wq = (const float*)d_in[1];
  const float* bq = (const float*)d_in[2];
  const float* wk = (const float*)d_in[3];
  const float* bk = (const float*)d_in[4];
  const float* wv = (const float*)d_in[5];
  const float* bv = (const float*)d_in[6];
  float* out = (float*)d_out;
  char* ws = (char*)d_ws;

  // Workspace layout (<=160 MB):
  //   [0,32M)      Qb bf16 [16384][1024]
  //   [32,64M)     Kb bf16 [16384][1024]
  //   [64,96M)     Vt bf16 [8][1024][2048]
  //   [96,130.1M)  Spk bf16 packed triangular [8][136*16384]
  //   [132,132.07M) sums fp32 [16384]
  //   [134,140M)   wb bf16 [3][1024][1024]
  //   xb (32MB @96M) aliases Spk: dead after qkv pass.
  u16* Qb = (u16*)(ws);
  u16* Kb = (u16*)(ws + ((size_t)32 << 20));
  u16* Vt = (u16*)(ws + ((size_t)64 << 20));
  u16* Spk = (u16*)(ws + ((size_t)96 << 20));
  u16* xb = (u16*)(ws + ((size_t)96 << 20));   // alias: dies before Spk written
  float* sums = (float*)(ws + ((size_t)132 << 20));
  u16* wb = (u16*)(ws + ((size_t)134 << 20));

  // pass 0: casts + sums zero-init
  cast_f32_to_bf16_kernel<<<16384, 256, 0, stream>>>(x, xb, 16777216 / 4);
  cast_w_kernel<<<dim3(512, 4), 256, 0, stream>>>(wq, wk, wv, wb, sums);

  // pass 1: persistent fused Q,K,V projections (V transposed), 256/block=CU
  qkv_kernel<<<256, 512, 0, stream>>>(xb, wb, bq, bk, bv, Qb, Kb, Vt);

  // pass 2: causal exp-scores, 256x128-tile 8-phase (packed layout unchanged)
  score_kernel<<<576, 512, 0, stream>>>(Kb, Qb, Spk, sums);

  // pass 3: P @ V, 256x128-tile 8-phase, scaled by 1/sums
  pv_kernel<<<512, 512, 0, stream>>>(Spk, Vt, sums, out);
}